// Round 1
// baseline (802.114 us; speedup 1.0000x reference)
//
#include <hip/hip_runtime.h>
#include <math.h>

namespace {

constexpr int B  = 8;
constexpr int S  = 4096;
constexpr int H  = 1024;
constexpr int NC = 16;
constexpr int NH = 4;
constexpr int HD = 256;
constexpr int H4 = 256;          // H/4 scorer hidden
constexpr int LH = NH * NC;      // 64 score rows per batch, lh = h*NC + l
constexpr float RSQRT_HD = 0.0625f;   // 1/sqrt(256)
constexpr float REPS = 1e-6f;

__device__ __forceinline__ float gelu_exact(float x) {
  return 0.5f * x * (1.0f + erff(x * 0.70710678118654752440f));
}

// ---------------- K0: q[l][o] = cq[l] . Wq[o] + bq[o] ----------------
__global__ __launch_bounds__(128) void k_q(const float* __restrict__ cq,
                                           const float* __restrict__ Wq,
                                           const float* __restrict__ bq,
                                           float* __restrict__ q) {
  const int l = blockIdx.x;
  const int o = blockIdx.y * 128 + threadIdx.x;
  __shared__ __align__(16) float cqs[H];
  for (int i = threadIdx.x; i < H; i += 128) cqs[i] = cq[l * H + i];
  __syncthreads();
  const float4* wr = (const float4*)(Wq + (size_t)o * H);
  const float4* cr = (const float4*)cqs;
  float acc = bq[o], acc2 = 0.f;
  for (int j = 0; j < H / 8; j++) {
    float4 w0 = wr[2 * j], w1 = wr[2 * j + 1];
    float4 c0 = cr[2 * j], c1 = cr[2 * j + 1];
    acc  = fmaf(w0.x, c0.x, acc);  acc  = fmaf(w0.y, c0.y, acc);
    acc  = fmaf(w0.z, c0.z, acc);  acc  = fmaf(w0.w, c0.w, acc);
    acc2 = fmaf(w1.x, c1.x, acc2); acc2 = fmaf(w1.y, c1.y, acc2);
    acc2 = fmaf(w1.z, c1.z, acc2); acc2 = fmaf(w1.w, c1.w, acc2);
  }
  q[l * H + o] = acc + acc2;
}

// -------- K1: qk_proj[lh][c] = (1/sqrt(HD)) * sum_d q[l][h*HD+d]*Wk[h*HD+d][c]
__global__ __launch_bounds__(256) void k_qkproj(const float* __restrict__ q,
                                                const float* __restrict__ Wk,
                                                float* __restrict__ qkp) {
  const int lh = blockIdx.x;            // lh = h*NC + l
  const int h = lh >> 4, l = lh & 15;
  const int c = blockIdx.y * 256 + threadIdx.x;
  __shared__ float qs[HD];
  qs[threadIdx.x] = q[l * H + h * HD + threadIdx.x];
  __syncthreads();
  float acc = 0.f, acc2 = 0.f;
  for (int d = 0; d < HD; d += 2) {
    acc  = fmaf(qs[d],     Wk[(size_t)(h * HD + d) * H + c],     acc);
    acc2 = fmaf(qs[d + 1], Wk[(size_t)(h * HD + d + 1) * H + c], acc2);
  }
  qkp[lh * H + c] = (acc + acc2) * RSQRT_HD;
}

// ---------------- K2: scorer MLP -> importance[tok] ----------------
// tile: 64 tokens x 256 hidden per block; thread (ti=tid>>5, ji=tid&31)
// owns 8 tokens (ti*8..) x 8 hidden units (ji, ji+32, ..., ji+224)
__global__ __launch_bounds__(256) void k_scorer(const float* __restrict__ te,
                                                const float* __restrict__ W1,
                                                const float* __restrict__ b1,
                                                const float* __restrict__ W2,
                                                const float* __restrict__ b2,
                                                float* __restrict__ imp) {
  __shared__ __align__(16) float te_sl[32][68];
  __shared__ float w1_sl[32][257];
  __shared__ float red[64][33];
  const int tid = threadIdx.x;
  const int ji = tid & 31;
  const int ti = tid >> 5;
  const int tok0 = blockIdx.x * 64;

  float acc[8][8];
#pragma unroll
  for (int a = 0; a < 8; a++)
#pragma unroll
    for (int bb = 0; bb < 8; bb++) acc[a][bb] = 0.f;

  for (int kk = 0; kk < H; kk += 32) {
#pragma unroll
    for (int i = 0; i < 8; i++) {
      int idx = tid + i * 256;
      int k = idx & 31, t = idx >> 5;
      te_sl[k][t] = te[(size_t)(tok0 + t) * H + kk + k];
    }
#pragma unroll
    for (int i = 0; i < 32; i++) {
      int idx = tid + i * 256;
      int k = idx & 31, j = idx >> 5;
      w1_sl[k][j] = W1[(size_t)j * H + kk + k];
    }
    __syncthreads();
#pragma unroll 4
    for (int k = 0; k < 32; k++) {
      float4 t0 = ((const float4*)&te_sl[k][ti * 8])[0];
      float4 t1 = ((const float4*)&te_sl[k][ti * 8])[1];
      float t8[8] = {t0.x, t0.y, t0.z, t0.w, t1.x, t1.y, t1.z, t1.w};
      float w[8];
#pragma unroll
      for (int jj = 0; jj < 8; jj++) w[jj] = w1_sl[k][ji + jj * 32];
#pragma unroll
      for (int t = 0; t < 8; t++)
#pragma unroll
        for (int jj = 0; jj < 8; jj++)
          acc[t][jj] = fmaf(t8[t], w[jj], acc[t][jj]);
    }
    __syncthreads();
  }
  float part[8];
#pragma unroll
  for (int t = 0; t < 8; t++) {
    float p = 0.f;
#pragma unroll
    for (int jj = 0; jj < 8; jj++) {
      int j = ji + jj * 32;
      float x = acc[t][jj] + b1[j];
      p = fmaf(gelu_exact(x), W2[j], p);
    }
    part[t] = p;
  }
#pragma unroll
  for (int t = 0; t < 8; t++) red[ti * 8 + t][ji] = part[t];
  __syncthreads();
  if (tid < 64) {
    float s = 0.f;
#pragma unroll 8
    for (int i = 0; i < 32; i++) s += red[tid][i];
    s += b2[0];
    imp[tok0 + tid] = 1.0f / (1.0f + expf(-s));
  }
}

// ---------------- K3: scores[b][lh][s] = imp[b,s] * (te[b,s] . qkp[lh]) ----
// tile: 64 tokens x 64 lh; thread owns 8 tokens x {ji, ji+32}
__global__ __launch_bounds__(256) void k_scores(const float* __restrict__ te,
                                                const float* __restrict__ qkp,
                                                const float* __restrict__ imp,
                                                float* __restrict__ sc) {
  __shared__ __align__(16) float te_sl[32][68];
  __shared__ float qk_sl[32][65];
  __shared__ float out_sl[64][65];
  __shared__ float imp_sl[64];
  const int tid = threadIdx.x;
  const int ji = tid & 31;
  const int ti = tid >> 5;
  const int b = blockIdx.y;
  const int s0 = blockIdx.x * 64;

  if (tid < 64) imp_sl[tid] = imp[b * S + s0 + tid];

  float acc[8][2];
#pragma unroll
  for (int t = 0; t < 8; t++) { acc[t][0] = 0.f; acc[t][1] = 0.f; }

  for (int kk = 0; kk < H; kk += 32) {
#pragma unroll
    for (int i = 0; i < 8; i++) {
      int idx = tid + i * 256;
      int k = idx & 31, t = idx >> 5;
      te_sl[k][t] = te[(size_t)(b * S + s0 + t) * H + kk + k];
    }
#pragma unroll
    for (int i = 0; i < 8; i++) {
      int idx = tid + i * 256;
      int lh = idx >> 5, k = idx & 31;
      qk_sl[k][lh] = qkp[(size_t)lh * H + kk + k];
    }
    __syncthreads();
#pragma unroll 4
    for (int k = 0; k < 32; k++) {
      float4 t0 = ((const float4*)&te_sl[k][ti * 8])[0];
      float4 t1 = ((const float4*)&te_sl[k][ti * 8])[1];
      float t8[8] = {t0.x, t0.y, t0.z, t0.w, t1.x, t1.y, t1.z, t1.w};
      float w0 = qk_sl[k][ji];
      float w1 = qk_sl[k][ji + 32];
#pragma unroll
      for (int t = 0; t < 8; t++) {
        acc[t][0] = fmaf(t8[t], w0, acc[t][0]);
        acc[t][1] = fmaf(t8[t], w1, acc[t][1]);
      }
    }
    __syncthreads();
  }
#pragma unroll
  for (int t = 0; t < 8; t++) {
    float im = imp_sl[ti * 8 + t];
    out_sl[ji][ti * 8 + t]      = acc[t][0] * im;
    out_sl[ji + 32][ti * 8 + t] = acc[t][1] * im;
  }
  __syncthreads();
#pragma unroll
  for (int i = 0; i < 16; i++) {
    int idx = tid + i * 256;
    int lh = idx >> 6, t = idx & 63;
    sc[(size_t)(b * LH + lh) * S + s0 + t] = out_sl[lh][t];
  }
}

// ---------------- K4: in-place softmax over S per row ----------------
__global__ __launch_bounds__(256) void k_softmax(float* __restrict__ sc) {
  const int tid = threadIdx.x;
  float4* row4 = (float4*)(sc + (size_t)blockIdx.x * S);
  __shared__ float redm[4];
  __shared__ float reds[4];
  float4 v[4];
  float m = -3.0e38f;
#pragma unroll
  for (int j = 0; j < 4; j++) {
    v[j] = row4[tid + j * 256];
    m = fmaxf(m, fmaxf(fmaxf(v[j].x, v[j].y), fmaxf(v[j].z, v[j].w)));
  }
#pragma unroll
  for (int off = 32; off; off >>= 1) m = fmaxf(m, __shfl_xor(m, off));
  if ((tid & 63) == 0) redm[tid >> 6] = m;
  __syncthreads();
  m = fmaxf(fmaxf(redm[0], redm[1]), fmaxf(redm[2], redm[3]));
  float ssum = 0.f;
#pragma unroll
  for (int j = 0; j < 4; j++) {
    v[j].x = expf(v[j].x - m); v[j].y = expf(v[j].y - m);
    v[j].z = expf(v[j].z - m); v[j].w = expf(v[j].w - m);
    ssum += (v[j].x + v[j].y) + (v[j].z + v[j].w);
  }
#pragma unroll
  for (int off = 32; off; off >>= 1) ssum += __shfl_xor(ssum, off);
  if ((tid & 63) == 0) reds[tid >> 6] = ssum;
  __syncthreads();
  ssum = (reds[0] + reds[1]) + (reds[2] + reds[3]);
  const float inv = 1.0f / ssum;
#pragma unroll
  for (int j = 0; j < 4; j++) {
    v[j].x *= inv; v[j].y *= inv; v[j].z *= inv; v[j].w *= inv;
    row4[tid + j * 256] = v[j];
  }
}

// ---------------- K4b: attn_weights = mean over heads ----------------
__global__ __launch_bounds__(256) void k_attnmean(const float* __restrict__ sc,
                                                  float* __restrict__ aw) {
  const int idx = blockIdx.x * 256 + threadIdx.x;  // float4 index
  const int b = idx >> 14;        // NC*S/4 = 16384 float4 per batch
  const int rem = idx & 16383;
  const int l = rem >> 10;        // S/4 = 1024 float4 per row
  const int s4 = rem & 1023;
  const float4* base = (const float4*)sc;
  float4 a0 = base[(size_t)(b * LH + 0 * NC + l) * (S / 4) + s4];
  float4 a1 = base[(size_t)(b * LH + 1 * NC + l) * (S / 4) + s4];
  float4 a2 = base[(size_t)(b * LH + 2 * NC + l) * (S / 4) + s4];
  float4 a3 = base[(size_t)(b * LH + 3 * NC + l) * (S / 4) + s4];
  float4 o;
  o.x = (a0.x + a1.x + a2.x + a3.x) * 0.25f;
  o.y = (a0.y + a1.y + a2.y + a3.y) * 0.25f;
  o.z = (a0.z + a1.z + a2.z + a3.z) * 0.25f;
  o.w = (a0.w + a1.w + a2.w + a3.w) * 0.25f;
  ((float4*)aw)[idx] = o;
}

// ---------------- K5: agg[b][lh][c] += sum_s attn[b][lh][s]*te[b][s][c] ----
__global__ __launch_bounds__(256) void k_agg(const float* __restrict__ attn,
                                             const float* __restrict__ te,
                                             float* __restrict__ agg) {
  __shared__ __align__(16) float at_sl[32][68];
  __shared__ __align__(16) float te_sl[32][128];
  const int tid = threadIdx.x;
  const int ji = tid & 31, ti = tid >> 5;
  const int cc = blockIdx.x;  // 8 chunks of 128 c
  const int sp = blockIdx.y;  // 8 splits of 512 s
  const int b = blockIdx.z;
  const int c0 = cc * 128;
  float acc[8][4];
#pragma unroll
  for (int t = 0; t < 8; t++)
#pragma unroll
    for (int g = 0; g < 4; g++) acc[t][g] = 0.f;

  for (int ss = sp * 512; ss < sp * 512 + 512; ss += 32) {
#pragma unroll
    for (int i = 0; i < 8; i++) {
      int idx = tid + i * 256;
      int lh = idx >> 5, s = idx & 31;
      at_sl[s][lh] = attn[(size_t)(b * LH + lh) * S + ss + s];
    }
#pragma unroll
    for (int i = 0; i < 16; i++) {
      int idx = tid + i * 256;
      int s = idx >> 7, c = idx & 127;
      te_sl[s][c] = te[(size_t)(b * S + ss + s) * H + c0 + c];
    }
    __syncthreads();
#pragma unroll 2
    for (int s = 0; s < 32; s++) {
      float4 a0 = ((const float4*)&at_sl[s][ti * 8])[0];
      float4 a1 = ((const float4*)&at_sl[s][ti * 8])[1];
      float a8[8] = {a0.x, a0.y, a0.z, a0.w, a1.x, a1.y, a1.z, a1.w};
      float t4[4];
#pragma unroll
      for (int g = 0; g < 4; g++) t4[g] = te_sl[s][ji + g * 32];
#pragma unroll
      for (int t = 0; t < 8; t++)
#pragma unroll
        for (int g = 0; g < 4; g++)
          acc[t][g] = fmaf(a8[t], t4[g], acc[t][g]);
    }
    __syncthreads();
  }
#pragma unroll
  for (int t = 0; t < 8; t++)
#pragma unroll
    for (int g = 0; g < 4; g++)
      atomicAdd(&agg[(size_t)(b * LH + ti * 8 + t) * H + c0 + ji + g * 32],
                acc[t][g]);
}

// ---------------- K6a: ctx[bl][h*HD+d] += Wv_h slice . agg ----------------
__global__ __launch_bounds__(256) void k_ctx(const float* __restrict__ agg,
                                             const float* __restrict__ Wv,
                                             float* __restrict__ ctx) {
  __shared__ __align__(16) float ag_sl[32][132];
  __shared__ float wv_sl[32][65];
  const int tid = threadIdx.x;
  const int ji = tid & 31, ti = tid >> 5;
  const int h = blockIdx.x;   // 4 heads
  const int dc = blockIdx.y;  // 4 chunks of 64 d
  const int cs = blockIdx.z;  // 4 splits of 256 c
  float acc[16][2];
#pragma unroll
  for (int m = 0; m < 16; m++) { acc[m][0] = 0.f; acc[m][1] = 0.f; }

  for (int sl = 0; sl < 256; sl += 32) {
#pragma unroll
    for (int i = 0; i < 16; i++) {
      int idx = tid + i * 256;
      int bl = idx >> 5, c = idx & 31;
      int row = (bl >> 4) * LH + h * NC + (bl & 15);
      ag_sl[c][bl] = agg[(size_t)row * H + cs * 256 + sl + c];
    }
#pragma unroll
    for (int i = 0; i < 8; i++) {
      int idx = tid + i * 256;
      int d = idx >> 5, c = idx & 31;
      wv_sl[c][d] = Wv[(size_t)(h * HD + dc * 64 + d) * H + cs * 256 + sl + c];
    }
    __syncthreads();
#pragma unroll 2
    for (int c = 0; c < 32; c++) {
      float am[16];
#pragma unroll
      for (int g = 0; g < 4; g++) {
        float4 a = ((const float4*)&ag_sl[c][ti * 16])[g];
        am[g * 4 + 0] = a.x; am[g * 4 + 1] = a.y;
        am[g * 4 + 2] = a.z; am[g * 4 + 3] = a.w;
      }
      float w0 = wv_sl[c][ji], w1 = wv_sl[c][ji + 32];
#pragma unroll
      for (int m = 0; m < 16; m++) {
        acc[m][0] = fmaf(am[m], w0, acc[m][0]);
        acc[m][1] = fmaf(am[m], w1, acc[m][1]);
      }
    }
    __syncthreads();
  }
#pragma unroll
  for (int m = 0; m < 16; m++) {
    int bl = ti * 16 + m;
    atomicAdd(&ctx[(size_t)bl * H + h * HD + dc * 64 + ji], acc[m][0]);
    atomicAdd(&ctx[(size_t)bl * H + h * HD + dc * 64 + ji + 32], acc[m][1]);
  }
}

// ---------------- K6b: outp[bl][o] += Wo[o] . (ctx[bl]+bv) ----------------
__global__ __launch_bounds__(256) void k_out(const float* __restrict__ ctx,
                                             const float* __restrict__ bv,
                                             const float* __restrict__ Wo,
                                             float* __restrict__ outp) {
  __shared__ __align__(16) float cx_sl[32][132];
  __shared__ float wo_sl[32][65];
  const int tid = threadIdx.x;
  const int ji = tid & 31, ti = tid >> 5;
  const int oc = blockIdx.x;  // 16 chunks of 64 o
  const int is = blockIdx.y;  // 4 splits of 256 i
  float acc[16][2];
#pragma unroll
  for (int m = 0; m < 16; m++) { acc[m][0] = 0.f; acc[m][1] = 0.f; }

  for (int sl = 0; sl < 256; sl += 32) {
#pragma unroll
    for (int i = 0; i < 16; i++) {
      int idx = tid + i * 256;
      int bl = idx >> 5, ii = idx & 31;
      int gi = is * 256 + sl + ii;
      cx_sl[ii][bl] = ctx[(size_t)bl * H + gi] + bv[gi];
    }
#pragma unroll
    for (int i = 0; i < 8; i++) {
      int idx = tid + i * 256;
      int o = idx >> 5, ii = idx & 31;
      wo_sl[ii][o] = Wo[(size_t)(oc * 64 + o) * H + is * 256 + sl + ii];
    }
    __syncthreads();
#pragma unroll 2
    for (int c = 0; c < 32; c++) {
      float am[16];
#pragma unroll
      for (int g = 0; g < 4; g++) {
        float4 a = ((const float4*)&cx_sl[c][ti * 16])[g];
        am[g * 4 + 0] = a.x; am[g * 4 + 1] = a.y;
        am[g * 4 + 2] = a.z; am[g * 4 + 3] = a.w;
      }
      float w0 = wo_sl[c][ji], w1 = wo_sl[c][ji + 32];
#pragma unroll
      for (int m = 0; m < 16; m++) {
        acc[m][0] = fmaf(am[m], w0, acc[m][0]);
        acc[m][1] = fmaf(am[m], w1, acc[m][1]);
      }
    }
    __syncthreads();
  }
#pragma unroll
  for (int m = 0; m < 16; m++) {
    int bl = ti * 16 + m;
    atomicAdd(&outp[(size_t)bl * H + oc * 64 + ji], acc[m][0]);
    atomicAdd(&outp[(size_t)bl * H + oc * 64 + ji + 32], acc[m][1]);
  }
}

// ---------------- K6c: RMSNorm -> compressed ----------------
__global__ __launch_bounds__(256) void k_rms(const float* __restrict__ outp,
                                             const float* __restrict__ bo,
                                             const float* __restrict__ rw,
                                             float* __restrict__ comp) {
  const int tid = threadIdx.x;
  const int bl = blockIdx.x;
  __shared__ float red[4];
  float4 v = ((const float4*)(outp + (size_t)bl * H))[tid];
  float4 bb = ((const float4*)bo)[tid];
  v.x += bb.x; v.y += bb.y; v.z += bb.z; v.w += bb.w;
  float ss = v.x * v.x + v.y * v.y + v.z * v.z + v.w * v.w;
#pragma unroll
  for (int off = 32; off; off >>= 1) ss += __shfl_xor(ss, off);
  if ((tid & 63) == 0) red[tid >> 6] = ss;
  __syncthreads();
  ss = (red[0] + red[1]) + (red[2] + red[3]);
  const float rms = sqrtf(ss * (1.0f / H) + REPS);
  const float inv = 1.0f / rms;
  float4 w = ((const float4*)rw)[tid];
  float4 o;
  o.x = v.x * inv * w.x; o.y = v.y * inv * w.y;
  o.z = v.z * inv * w.z; o.w = v.w * inv * w.w;
  ((float4*)(comp + (size_t)bl * H))[tid] = o;
}

}  // namespace

extern "C" void kernel_launch(void* const* d_in, const int* in_sizes, int n_in,
                              void* d_out, int out_size, void* d_ws,
                              size_t ws_size, hipStream_t stream) {
  (void)in_sizes; (void)n_in; (void)out_size; (void)ws_size;
  const float* te   = (const float*)d_in[0];
  const float* W1   = (const float*)d_in[1];
  const float* b1   = (const float*)d_in[2];
  const float* W2   = (const float*)d_in[3];
  const float* b2   = (const float*)d_in[4];
  const float* cq   = (const float*)d_in[5];
  const float* Wq   = (const float*)d_in[6];
  const float* bq   = (const float*)d_in[7];
  const float* Wk   = (const float*)d_in[8];
  // d_in[9] = bk: its score contribution is constant over s -> softmax-invariant
  const float* Wv   = (const float*)d_in[10];
  const float* bv   = (const float*)d_in[11];
  const float* Wo   = (const float*)d_in[12];
  const float* bo   = (const float*)d_in[13];
  const float* rmsw = (const float*)d_in[14];

  float* out_comp = (float*)d_out;              // [B][NC][H]   = 131072
  float* out_imp  = out_comp + B * NC * H;      // [B][S]       =  32768
  float* out_attw = out_imp + B * S;            // [B][NC][S]   = 524288

  float* q    = (float*)d_ws;                   //  16384
  float* qkp  = q + NC * H;                     //  65536
  float* sc   = qkp + LH * H;                   // 2097152 (scores/attn)
  float* agg  = sc + (size_t)B * LH * S;        //  524288 (atomic, zeroed)
  float* ctx  = agg + (size_t)B * LH * H;       //  131072 (atomic, zeroed)
  float* outp = ctx + (size_t)B * NC * H;       //  131072 (atomic, zeroed)

  // zero the three atomic-accumulated buffers (contiguous region, 3 MB)
  hipMemsetAsync(agg, 0, (size_t)(B * LH * H + 2 * B * NC * H) * sizeof(float),
                 stream);

  k_q<<<dim3(NC, H / 128), 128, 0, stream>>>(cq, Wq, bq, q);
  k_qkproj<<<dim3(LH, H / 256), 256, 0, stream>>>(q, Wk, qkp);
  k_scorer<<<B * S / 64, 256, 0, stream>>>(te, W1, b1, W2, b2, out_imp);
  k_scores<<<dim3(S / 64, B), 256, 0, stream>>>(te, qkp, out_imp, sc);
  k_softmax<<<B * LH, 256, 0, stream>>>(sc);
  k_attnmean<<<B * NC * S / 4 / 256, 256, 0, stream>>>(sc, out_attw);
  k_agg<<<dim3(8, 8, 8), 256, 0, stream>>>(sc, te, agg);
  k_ctx<<<dim3(4, 4, 4), 256, 0, stream>>>(agg, Wv, ctx);
  k_out<<<dim3(16, 4), 256, 0, stream>>>(ctx, bv, Wo, outp);
  k_rms<<<B * NC, 256, 0, stream>>>(outp, bo, rmsw, out_comp);
}

// Round 2
// 566.806 us; speedup vs baseline: 1.4151x; 1.4151x over previous
//
#include <hip/hip_runtime.h>
#include <math.h>

namespace {

constexpr int B  = 8;
constexpr int S  = 4096;
constexpr int H  = 1024;
constexpr int NC = 16;
constexpr int NH = 4;
constexpr int HD = 256;
constexpr int LH = NH * NC;      // 64 score rows per batch, lh = h*NC + l
constexpr float RSQRT_HD = 0.0625f;   // 1/sqrt(256)
constexpr float REPS = 1e-6f;

typedef __attribute__((ext_vector_type(8))) short bhalf8;
typedef __attribute__((ext_vector_type(4))) short bhalf4;
typedef __attribute__((ext_vector_type(4))) float floatx4;

__device__ __forceinline__ unsigned short f2bf(float f) {
  unsigned u = __builtin_bit_cast(unsigned, f);
  u += 0x7fffu + ((u >> 16) & 1u);          // RNE
  return (unsigned short)(u >> 16);
}

__device__ __forceinline__ float gelu_exact(float x) {
  return 0.5f * x * (1.0f + erff(x * 0.70710678118654752440f));
}

// ---------------- K_prep: W1 fp32 -> bf16 copy ----------------
__global__ __launch_bounds__(256) void k_prep(const float* __restrict__ W1,
                                              unsigned short* __restrict__ W1b) {
  int i = blockIdx.x * 256 + threadIdx.x;   // float4 granule; 65536 total
  float4 v = ((const float4*)W1)[i];
  bhalf4 o;
  o.x = (short)f2bf(v.x); o.y = (short)f2bf(v.y);
  o.z = (short)f2bf(v.z); o.w = (short)f2bf(v.w);
  ((bhalf4*)W1b)[i] = o;
}

// ---------------- K0: q[l][o] = cq[l] . Wq[o] + bq[o] ----------------
__global__ __launch_bounds__(128) void k_q(const float* __restrict__ cq,
                                           const float* __restrict__ Wq,
                                           const float* __restrict__ bq,
                                           float* __restrict__ q) {
  const int l = blockIdx.x;
  const int o = blockIdx.y * 128 + threadIdx.x;
  __shared__ __align__(16) float cqs[H];
  for (int i = threadIdx.x; i < H; i += 128) cqs[i] = cq[l * H + i];
  __syncthreads();
  const float4* wr = (const float4*)(Wq + (size_t)o * H);
  const float4* cr = (const float4*)cqs;
  float acc = bq[o], acc2 = 0.f;
  for (int j = 0; j < H / 8; j++) {
    float4 w0 = wr[2 * j], w1 = wr[2 * j + 1];
    float4 c0 = cr[2 * j], c1 = cr[2 * j + 1];
    acc  = fmaf(w0.x, c0.x, acc);  acc  = fmaf(w0.y, c0.y, acc);
    acc  = fmaf(w0.z, c0.z, acc);  acc  = fmaf(w0.w, c0.w, acc);
    acc2 = fmaf(w1.x, c1.x, acc2); acc2 = fmaf(w1.y, c1.y, acc2);
    acc2 = fmaf(w1.z, c1.z, acc2); acc2 = fmaf(w1.w, c1.w, acc2);
  }
  q[l * H + o] = acc + acc2;
}

// -------- K1: qkp[lh][c] = bf16( (1/sqrt(HD)) * sum_d q[l][h*HD+d]*Wk[h*HD+d][c] )
__global__ __launch_bounds__(256) void k_qkproj(const float* __restrict__ q,
                                                const float* __restrict__ Wk,
                                                unsigned short* __restrict__ qkpb) {
  const int lh = blockIdx.x;            // lh = h*NC + l
  const int h = lh >> 4, l = lh & 15;
  const int c = blockIdx.y * 256 + threadIdx.x;
  __shared__ float qs[HD];
  qs[threadIdx.x] = q[l * H + h * HD + threadIdx.x];
  __syncthreads();
  float acc = 0.f, acc2 = 0.f;
  for (int d = 0; d < HD; d += 2) {
    acc  = fmaf(qs[d],     Wk[(size_t)(h * HD + d) * H + c],     acc);
    acc2 = fmaf(qs[d + 1], Wk[(size_t)(h * HD + d + 1) * H + c], acc2);
  }
  qkpb[lh * H + c] = f2bf((acc + acc2) * RSQRT_HD);
}

// ---------------- K2: fused scorer MLP + scores via bf16 MFMA ----------------
// block = 256 thr (4 waves), M-tile = 128 tokens, K-chunk = 64.
// GEMM1: hid = te . W1^T  (N=256), GEMM2: raw = te . qkp^T (N=64), shared A.
// epilogue: imp = sigmoid(gelu(hid+b1).W2+b2); sc = raw*imp, transposed to [lh][s].
__global__ __launch_bounds__(256) void k_fused(
    const float* __restrict__ te, const unsigned short* __restrict__ W1b,
    const float* __restrict__ b1, const float* __restrict__ W2,
    const float* __restrict__ b2, const unsigned short* __restrict__ qkpb,
    float* __restrict__ imp, float* __restrict__ sc) {
  // LDS map (all bf16 tiles XOR-swizzled by ((row&7)<<4) on the byte offset):
  //   [0,     16384) te  [128][64] bf16
  //   [16384, 49152) W1  [256][64] bf16
  //   [49152, 57344) qkp [64][64]  bf16
  //   [57344, 59392) b1s[256], w2s[256] fp32
  //   alias [0, 34304): sl fp32 [128][67] score transpose buffer
  __shared__ __align__(16) char smem[59392];
  const int tid  = threadIdx.x;
  const int lane = tid & 63;
  const int w    = tid >> 6;        // wave 0..3
  const int l15  = lane & 15;
  const int lk   = lane >> 4;       // k-group 0..3
  const int tok0 = blockIdx.x * 128;

  float* b1s = (float*)(smem + 57344);
  float* w2s = b1s + 256;
  b1s[tid] = b1[tid];
  w2s[tid] = W2[tid];

  floatx4 acc1[2][16];
  floatx4 acc2[2][4];
#pragma unroll
  for (int mf = 0; mf < 2; mf++) {
#pragma unroll
    for (int nf = 0; nf < 16; nf++) acc1[mf][nf] = 0.f;
#pragma unroll
    for (int nf = 0; nf < 4; nf++) acc2[mf][nf] = 0.f;
  }

  for (int kk = 0; kk < H; kk += 64) {
    __syncthreads();  // previous iter's LDS reads done before overwrite
    // ---- stage te (fp32 -> bf16) ----
#pragma unroll
    for (int i = 0; i < 8; i++) {
      int idx = tid + i * 256;
      int row = idx >> 4, k4 = idx & 15;
      float4 v = *(const float4*)(te + (size_t)(tok0 + row) * H + kk + k4 * 4);
      bhalf4 o;
      o.x = (short)f2bf(v.x); o.y = (short)f2bf(v.y);
      o.z = (short)f2bf(v.z); o.w = (short)f2bf(v.w);
      int byteo = (row * 128 + k4 * 8) ^ ((row & 7) << 4);
      *(bhalf4*)(smem + byteo) = o;
    }
    // ---- stage W1 (bf16 direct) ----
#pragma unroll
    for (int i = 0; i < 8; i++) {
      int idx = tid + i * 256;
      int row = idx >> 3, k8 = idx & 7;
      bhalf8 v = *(const bhalf8*)(W1b + (size_t)row * H + kk + k8 * 8);
      int byteo = 16384 + ((row * 128 + k8 * 16) ^ ((row & 7) << 4));
      *(bhalf8*)(smem + byteo) = v;
    }
    // ---- stage qkp (bf16 direct) ----
#pragma unroll
    for (int i = 0; i < 2; i++) {
      int idx = tid + i * 256;
      int row = idx >> 3, k8 = idx & 7;
      bhalf8 v = *(const bhalf8*)(qkpb + (size_t)row * H + kk + k8 * 8);
      int byteo = 49152 + ((row * 128 + k8 * 16) ^ ((row & 7) << 4));
      *(bhalf8*)(smem + byteo) = v;
    }
    __syncthreads();
    // ---- MFMA: 2 k-steps of 32 ----
#pragma unroll
    for (int ks = 0; ks < 2; ks++) {
      bhalf8 a[2];
#pragma unroll
      for (int mf = 0; mf < 2; mf++) {
        int row = w * 32 + mf * 16 + l15;
        int byteo = (row * 128 + (ks * 32 + lk * 8) * 2) ^ ((row & 7) << 4);
        a[mf] = *(bhalf8*)(smem + byteo);
      }
#pragma unroll
      for (int nf = 0; nf < 16; nf++) {
        int j = nf * 16 + l15;
        int byteo = 16384 + ((j * 128 + (ks * 32 + lk * 8) * 2) ^ ((j & 7) << 4));
        bhalf8 bfr = *(bhalf8*)(smem + byteo);
        acc1[0][nf] = __builtin_amdgcn_mfma_f32_16x16x32_bf16(a[0], bfr, acc1[0][nf], 0, 0, 0);
        acc1[1][nf] = __builtin_amdgcn_mfma_f32_16x16x32_bf16(a[1], bfr, acc1[1][nf], 0, 0, 0);
      }
#pragma unroll
      for (int nf = 0; nf < 4; nf++) {
        int j = nf * 16 + l15;
        int byteo = 49152 + ((j * 128 + (ks * 32 + lk * 8) * 2) ^ ((j & 7) << 4));
        bhalf8 bfr = *(bhalf8*)(smem + byteo);
        acc2[0][nf] = __builtin_amdgcn_mfma_f32_16x16x32_bf16(a[0], bfr, acc2[0][nf], 0, 0, 0);
        acc2[1][nf] = __builtin_amdgcn_mfma_f32_16x16x32_bf16(a[1], bfr, acc2[1][nf], 0, 0, 0);
      }
    }
  }

  // ---- epilogue: layer-2 + sigmoid -> imp ----
  const float b2v = b2[0];
  float impv[2][4];
#pragma unroll
  for (int mf = 0; mf < 2; mf++) {
#pragma unroll
    for (int reg = 0; reg < 4; reg++) {
      float p = 0.f;
#pragma unroll
      for (int nf = 0; nf < 16; nf++) {
        int j = nf * 16 + l15;
        float x = acc1[mf][nf][reg] + b1s[j];
        p = fmaf(gelu_exact(x), w2s[j], p);
      }
      p += __shfl_xor(p, 1); p += __shfl_xor(p, 2);
      p += __shfl_xor(p, 4); p += __shfl_xor(p, 8);
      float im = 1.0f / (1.0f + expf(-(p + b2v)));
      impv[mf][reg] = im;
      if (l15 == 0)
        imp[tok0 + w * 32 + mf * 16 + lk * 4 + reg] = im;
    }
  }

  // ---- scale scores by imp and transpose via LDS ----
  __syncthreads();
  float* sl = (float*)smem;   // [128 s][67] (odd pad -> <=3-way on store, 2-way on read)
#pragma unroll
  for (int mf = 0; mf < 2; mf++)
#pragma unroll
    for (int nf = 0; nf < 4; nf++)
#pragma unroll
      for (int reg = 0; reg < 4; reg++) {
        int col = nf * 16 + l15;
        int row = w * 32 + mf * 16 + lk * 4 + reg;
        sl[row * 67 + col] = acc2[mf][nf][reg] * impv[mf][reg];
      }
  __syncthreads();
  const int bb = tok0 >> 12;
  const int s0 = tok0 & (S - 1);
#pragma unroll
  for (int i = 0; i < 32; i++) {
    int idx = tid + i * 256;
    int lh = idx >> 7, s = idx & 127;
    sc[(size_t)(bb * LH + lh) * S + s0 + s] = sl[s * 67 + lh];
  }
}

// ---------------- K4: in-place softmax over S per row ----------------
__global__ __launch_bounds__(256) void k_softmax(float* __restrict__ sc) {
  const int tid = threadIdx.x;
  float4* row4 = (float4*)(sc + (size_t)blockIdx.x * S);
  __shared__ float redm[4];
  __shared__ float reds[4];
  float4 v[4];
  float m = -3.0e38f;
#pragma unroll
  for (int j = 0; j < 4; j++) {
    v[j] = row4[tid + j * 256];
    m = fmaxf(m, fmaxf(fmaxf(v[j].x, v[j].y), fmaxf(v[j].z, v[j].w)));
  }
#pragma unroll
  for (int off = 32; off; off >>= 1) m = fmaxf(m, __shfl_xor(m, off));
  if ((tid & 63) == 0) redm[tid >> 6] = m;
  __syncthreads();
  m = fmaxf(fmaxf(redm[0], redm[1]), fmaxf(redm[2], redm[3]));
  float ssum = 0.f;
#pragma unroll
  for (int j = 0; j < 4; j++) {
    v[j].x = expf(v[j].x - m); v[j].y = expf(v[j].y - m);
    v[j].z = expf(v[j].z - m); v[j].w = expf(v[j].w - m);
    ssum += (v[j].x + v[j].y) + (v[j].z + v[j].w);
  }
#pragma unroll
  for (int off = 32; off; off >>= 1) ssum += __shfl_xor(ssum, off);
  if ((tid & 63) == 0) reds[tid >> 6] = ssum;
  __syncthreads();
  ssum = (reds[0] + reds[1]) + (reds[2] + reds[3]);
  const float inv = 1.0f / ssum;
#pragma unroll
  for (int j = 0; j < 4; j++) {
    v[j].x *= inv; v[j].y *= inv; v[j].z *= inv; v[j].w *= inv;
    row4[tid + j * 256] = v[j];
  }
}

// ---------------- K4b: attn_weights = mean over heads ----------------
__global__ __launch_bounds__(256) void k_attnmean(const float* __restrict__ sc,
                                                  float* __restrict__ aw) {
  const int idx = blockIdx.x * 256 + threadIdx.x;  // float4 index
  const int b = idx >> 14;
  const int rem = idx & 16383;
  const int l = rem >> 10;
  const int s4 = rem & 1023;
  const float4* base = (const float4*)sc;
  float4 a0 = base[(size_t)(b * LH + 0 * NC + l) * (S / 4) + s4];
  float4 a1 = base[(size_t)(b * LH + 1 * NC + l) * (S / 4) + s4];
  float4 a2 = base[(size_t)(b * LH + 2 * NC + l) * (S / 4) + s4];
  float4 a3 = base[(size_t)(b * LH + 3 * NC + l) * (S / 4) + s4];
  float4 o;
  o.x = (a0.x + a1.x + a2.x + a3.x) * 0.25f;
  o.y = (a0.y + a1.y + a2.y + a3.y) * 0.25f;
  o.z = (a0.z + a1.z + a2.z + a3.z) * 0.25f;
  o.w = (a0.w + a1.w + a2.w + a3.w) * 0.25f;
  ((float4*)aw)[idx] = o;
}

// ---------------- K5: agg[b][lh][c] += sum_s attn[b][lh][s]*te[b][s][c] ----
__global__ __launch_bounds__(256) void k_agg(const float* __restrict__ attn,
                                             const float* __restrict__ te,
                                             float* __restrict__ agg) {
  __shared__ __align__(16) float at_sl[32][68];
  __shared__ __align__(16) float te_sl[32][128];
  const int tid = threadIdx.x;
  const int ji = tid & 31, ti = tid >> 5;
  const int cc = blockIdx.x;  // 8 chunks of 128 c
  const int sp = blockIdx.y;  // 8 splits of 512 s
  const int b = blockIdx.z;
  const int c0 = cc * 128;
  float acc[8][4];
#pragma unroll
  for (int t = 0; t < 8; t++)
#pragma unroll
    for (int g = 0; g < 4; g++) acc[t][g] = 0.f;

  for (int ss = sp * 512; ss < sp * 512 + 512; ss += 32) {
#pragma unroll
    for (int i = 0; i < 8; i++) {
      int idx = tid + i * 256;
      int lh = idx >> 5, s = idx & 31;
      at_sl[s][lh] = attn[(size_t)(b * LH + lh) * S + ss + s];
    }
#pragma unroll
    for (int i = 0; i < 16; i++) {
      int idx = tid + i * 256;
      int s = idx >> 7, c = idx & 127;
      te_sl[s][c] = te[(size_t)(b * S + ss + s) * H + c0 + c];
    }
    __syncthreads();
#pragma unroll 2
    for (int s = 0; s < 32; s++) {
      float4 a0 = ((const float4*)&at_sl[s][ti * 8])[0];
      float4 a1 = ((const float4*)&at_sl[s][ti * 8])[1];
      float a8[8] = {a0.x, a0.y, a0.z, a0.w, a1.x, a1.y, a1.z, a1.w};
      float t4[4];
#pragma unroll
      for (int g = 0; g < 4; g++) t4[g] = te_sl[s][ji + g * 32];
#pragma unroll
      for (int t = 0; t < 8; t++)
#pragma unroll
        for (int g = 0; g < 4; g++)
          acc[t][g] = fmaf(a8[t], t4[g], acc[t][g]);
    }
    __syncthreads();
  }
#pragma unroll
  for (int t = 0; t < 8; t++)
#pragma unroll
    for (int g = 0; g < 4; g++)
      atomicAdd(&agg[(size_t)(b * LH + ti * 8 + t) * H + c0 + ji + g * 32],
                acc[t][g]);
}

// ---------------- K6a: ctx[bl][h*HD+d] += Wv_h slice . agg ----------------
__global__ __launch_bounds__(256) void k_ctx(const float* __restrict__ agg,
                                             const float* __restrict__ Wv,
                                             float* __restrict__ ctx) {
  __shared__ __align__(16) float ag_sl[32][132];
  __shared__ float wv_sl[32][65];
  const int tid = threadIdx.x;
  const int ji = tid & 31, ti = tid >> 5;
  const int h = blockIdx.x;
  const int dc = blockIdx.y;
  const int cs = blockIdx.z;
  float acc[16][2];
#pragma unroll
  for (int m = 0; m < 16; m++) { acc[m][0] = 0.f; acc[m][1] = 0.f; }

  for (int sl = 0; sl < 256; sl += 32) {
#pragma unroll
    for (int i = 0; i < 16; i++) {
      int idx = tid + i * 256;
      int bl = idx >> 5, c = idx & 31;
      int row = (bl >> 4) * LH + h * NC + (bl & 15);
      ag_sl[c][bl] = agg[(size_t)row * H + cs * 256 + sl + c];
    }
#pragma unroll
    for (int i = 0; i < 8; i++) {
      int idx = tid + i * 256;
      int d = idx >> 5, c = idx & 31;
      wv_sl[c][d] = Wv[(size_t)(h * HD + dc * 64 + d) * H + cs * 256 + sl + c];
    }
    __syncthreads();
#pragma unroll 2
    for (int c = 0; c < 32; c++) {
      float am[16];
#pragma unroll
      for (int g = 0; g < 4; g++) {
        float4 a = ((const float4*)&ag_sl[c][ti * 16])[g];
        am[g * 4 + 0] = a.x; am[g * 4 + 1] = a.y;
        am[g * 4 + 2] = a.z; am[g * 4 + 3] = a.w;
      }
      float w0 = wv_sl[c][ji], w1 = wv_sl[c][ji + 32];
#pragma unroll
      for (int m = 0; m < 16; m++) {
        acc[m][0] = fmaf(am[m], w0, acc[m][0]);
        acc[m][1] = fmaf(am[m], w1, acc[m][1]);
      }
    }
    __syncthreads();
  }
#pragma unroll
  for (int m = 0; m < 16; m++) {
    int bl = ti * 16 + m;
    atomicAdd(&ctx[(size_t)bl * H + h * HD + dc * 64 + ji], acc[m][0]);
    atomicAdd(&ctx[(size_t)bl * H + h * HD + dc * 64 + ji + 32], acc[m][1]);
  }
}

// ---------------- K6b: outp[bl][o] += Wo[o] . (ctx[bl]+bv) ----------------
__global__ __launch_bounds__(256) void k_out(const float* __restrict__ ctx,
                                             const float* __restrict__ bv,
                                             const float* __restrict__ Wo,
                                             float* __restrict__ outp) {
  __shared__ __align__(16) float cx_sl[32][132];
  __shared__ float wo_sl[32][65];
  const int tid = threadIdx.x;
  const int ji = tid & 31, ti = tid >> 5;
  const int oc = blockIdx.x;
  const int is = blockIdx.y;
  float acc[16][2];
#pragma unroll
  for (int m = 0; m < 16; m++) { acc[m][0] = 0.f; acc[m][1] = 0.f; }

  for (int sl = 0; sl < 256; sl += 32) {
#pragma unroll
    for (int i = 0; i < 16; i++) {
      int idx = tid + i * 256;
      int bl = idx >> 5, ii = idx & 31;
      int gi = is * 256 + sl + ii;
      cx_sl[ii][bl] = ctx[(size_t)bl * H + gi] + bv[gi];
    }
#pragma unroll
    for (int i = 0; i < 8; i++) {
      int idx = tid + i * 256;
      int o = idx >> 5, ii = idx & 31;
      wo_sl[ii][o] = Wo[(size_t)(oc * 64 + o) * H + is * 256 + sl + ii];
    }
    __syncthreads();
#pragma unroll 2
    for (int c = 0; c < 32; c++) {
      float am[16];
#pragma unroll
      for (int g = 0; g < 4; g++) {
        float4 a = ((const float4*)&cx_sl[c][ti * 16])[g];
        am[g * 4 + 0] = a.x; am[g * 4 + 1] = a.y;
        am[g * 4 + 2] = a.z; am[g * 4 + 3] = a.w;
      }
      float w0 = wo_sl[c][ji], w1 = wo_sl[c][ji + 32];
#pragma unroll
      for (int m = 0; m < 16; m++) {
        acc[m][0] = fmaf(am[m], w0, acc[m][0]);
        acc[m][1] = fmaf(am[m], w1, acc[m][1]);
      }
    }
    __syncthreads();
  }
#pragma unroll
  for (int m = 0; m < 16; m++) {
    int bl = ti * 16 + m;
    atomicAdd(&outp[(size_t)bl * H + oc * 64 + ji], acc[m][0]);
    atomicAdd(&outp[(size_t)bl * H + oc * 64 + ji + 32], acc[m][1]);
  }
}

// ---------------- K6c: RMSNorm -> compressed ----------------
__global__ __launch_bounds__(256) void k_rms(const float* __restrict__ outp,
                                             const float* __restrict__ bo,
                                             const float* __restrict__ rw,
                                             float* __restrict__ comp) {
  const int tid = threadIdx.x;
  const int bl = blockIdx.x;
  __shared__ float red[4];
  float4 v = ((const float4*)(outp + (size_t)bl * H))[tid];
  float4 bb = ((const float4*)bo)[tid];
  v.x += bb.x; v.y += bb.y; v.z += bb.z; v.w += bb.w;
  float ss = v.x * v.x + v.y * v.y + v.z * v.z + v.w * v.w;
#pragma unroll
  for (int off = 32; off; off >>= 1) ss += __shfl_xor(ss, off);
  if ((tid & 63) == 0) red[tid >> 6] = ss;
  __syncthreads();
  ss = (red[0] + red[1]) + (red[2] + red[3]);
  const float rms = sqrtf(ss * (1.0f / H) + REPS);
  const float inv = 1.0f / rms;
  float4 w = ((const float4*)rw)[tid];
  float4 o;
  o.x = v.x * inv * w.x; o.y = v.y * inv * w.y;
  o.z = v.z * inv * w.z; o.w = v.w * inv * w.w;
  ((float4*)(comp + (size_t)bl * H))[tid] = o;
}

}  // namespace

extern "C" void kernel_launch(void* const* d_in, const int* in_sizes, int n_in,
                              void* d_out, int out_size, void* d_ws,
                              size_t ws_size, hipStream_t stream) {
  (void)in_sizes; (void)n_in; (void)out_size; (void)ws_size;
  const float* te   = (const float*)d_in[0];
  const float* W1   = (const float*)d_in[1];
  const float* b1   = (const float*)d_in[2];
  const float* W2   = (const float*)d_in[3];
  const float* b2   = (const float*)d_in[4];
  const float* cq   = (const float*)d_in[5];
  const float* Wq   = (const float*)d_in[6];
  const float* bq   = (const float*)d_in[7];
  const float* Wk   = (const float*)d_in[8];
  // d_in[9] = bk: constant over s -> softmax-invariant, dropped
  const float* Wv   = (const float*)d_in[10];
  const float* bv   = (const float*)d_in[11];
  const float* Wo   = (const float*)d_in[12];
  const float* bo   = (const float*)d_in[13];
  const float* rmsw = (const float*)d_in[14];

  float* out_comp = (float*)d_out;              // [B][NC][H]   = 131072
  float* out_imp  = out_comp + B * NC * H;      // [B][S]       =  32768
  float* out_attw = out_imp + B * S;            // [B][NC][S]   = 524288

  float* q    = (float*)d_ws;                   //  16384 f
  float* qkp_region = q + NC * H;               //  65536 f slot (ushort qkp uses half)
  unsigned short* qkpb = (unsigned short*)qkp_region;
  float* sc   = qkp_region + LH * H;            // 2097152 f (scores/attn)
  float* agg  = sc + (size_t)B * LH * S;        //  524288 f (atomic, zeroed)
  float* ctx  = agg + (size_t)B * LH * H;       //  131072 f (atomic, zeroed)
  float* outp = ctx + (size_t)B * NC * H;       //  131072 f (atomic, zeroed)
  unsigned short* W1b = (unsigned short*)(outp + B * NC * H);  // 262144 us

  hipMemsetAsync(agg, 0, (size_t)(B * LH * H + 2 * B * NC * H) * sizeof(float),
                 stream);

  k_prep<<<256, 256, 0, stream>>>(W1, W1b);
  k_q<<<dim3(NC, H / 128), 128, 0, stream>>>(cq, Wq, bq, q);
  k_qkproj<<<dim3(LH, H / 256), 256, 0, stream>>>(q, Wk, qkpb);
  k_fused<<<B * S / 128, 256, 0, stream>>>(te, W1b, b1, W2, b2, qkpb,
                                           out_imp, sc);
  k_softmax<<<B * LH, 256, 0, stream>>>(sc);
  k_attnmean<<<B * NC * S / 4 / 256, 256, 0, stream>>>(sc, out_attw);
  k_agg<<<dim3(8, 8, 8), 256, 0, stream>>>(sc, te, agg);
  k_ctx<<<dim3(4, 4, 4), 256, 0, stream>>>(agg, Wv, ctx);
  k_out<<<dim3(16, 4), 256, 0, stream>>>(ctx, bv, Wo, outp);
  k_rms<<<B * NC, 256, 0, stream>>>(outp, bo, rmsw, out_comp);
}

// Round 3
// 445.538 us; speedup vs baseline: 1.8003x; 1.2722x over previous
//
#include <hip/hip_runtime.h>
#include <math.h>

namespace {

constexpr int B  = 8;
constexpr int S  = 4096;
constexpr int H  = 1024;
constexpr int NC = 16;
constexpr int NH = 4;
constexpr int HD = 256;
constexpr int LH = NH * NC;      // 64 score rows per batch, lh = h*NC + l
constexpr float RSQRT_HD = 0.0625f;   // 1/sqrt(256)
constexpr float REPS = 1e-6f;

typedef __attribute__((ext_vector_type(8))) short bhalf8;
typedef __attribute__((ext_vector_type(4))) short bhalf4;
typedef __attribute__((ext_vector_type(4))) float floatx4;

__device__ __forceinline__ unsigned short f2bf(float f) {
  unsigned u = __builtin_bit_cast(unsigned, f);
  u += 0x7fffu + ((u >> 16) & 1u);          // RNE
  return (unsigned short)(u >> 16);
}

__device__ __forceinline__ float gelu_exact(float x) {
  return 0.5f * x * (1.0f + erff(x * 0.70710678118654752440f));
}

// ---------------- K_prep: W1 fp32 -> bf16 copy ----------------
__global__ __launch_bounds__(256) void k_prep(const float* __restrict__ W1,
                                              unsigned short* __restrict__ W1b) {
  int i = blockIdx.x * 256 + threadIdx.x;   // float4 granule; 65536 total
  float4 v = ((const float4*)W1)[i];
  bhalf4 o;
  o.x = (short)f2bf(v.x); o.y = (short)f2bf(v.y);
  o.z = (short)f2bf(v.z); o.w = (short)f2bf(v.w);
  ((bhalf4*)W1b)[i] = o;
}

// ---------------- K0: q[l][o] = cq[l] . Wq[o] + bq[o] ----------------
// wave-cooperative: whole wave does one output row dot (coalesced Wq reads)
__global__ __launch_bounds__(256) void k_q(const float* __restrict__ cq,
                                           const float* __restrict__ Wq,
                                           const float* __restrict__ bq,
                                           float* __restrict__ q) {
  const int l = blockIdx.x;
  const int oc = blockIdx.y;                // 8 chunks of 128 o
  const int lane = threadIdx.x & 63;
  const int w = threadIdx.x >> 6;
  __shared__ __align__(16) float cqs[H];
  for (int i = threadIdx.x; i < H; i += 256) cqs[i] = cq[l * H + i];
  __syncthreads();
  float4 c4[4];
#pragma unroll
  for (int j = 0; j < 4; j++) c4[j] = ((const float4*)cqs)[lane * 4 + j];
  for (int oo = 0; oo < 32; oo++) {
    int o = oc * 128 + w * 32 + oo;
    const float4* wr = (const float4*)(Wq + (size_t)o * H) + lane * 4;
    float p = 0.f;
#pragma unroll
    for (int j = 0; j < 4; j++) {
      float4 wv = wr[j];
      p = fmaf(wv.x, c4[j].x, p); p = fmaf(wv.y, c4[j].y, p);
      p = fmaf(wv.z, c4[j].z, p); p = fmaf(wv.w, c4[j].w, p);
    }
#pragma unroll
    for (int off = 32; off; off >>= 1) p += __shfl_xor(p, off);
    if (lane == 0) q[l * H + o] = p + bq[o];
  }
}

// -------- K1: qkp[lh][c] = bf16( (1/sqrt(HD)) * sum_d q[l][h*HD+d]*Wk[h*HD+d][c] )
__global__ __launch_bounds__(256) void k_qkproj(const float* __restrict__ q,
                                                const float* __restrict__ Wk,
                                                unsigned short* __restrict__ qkpb) {
  const int lh = blockIdx.x;            // lh = h*NC + l
  const int h = lh >> 4, l = lh & 15;
  const int c = blockIdx.y * 256 + threadIdx.x;
  __shared__ float qs[HD];
  qs[threadIdx.x] = q[l * H + h * HD + threadIdx.x];
  __syncthreads();
  float acc = 0.f, acc2 = 0.f;
  for (int d = 0; d < HD; d += 2) {
    acc  = fmaf(qs[d],     Wk[(size_t)(h * HD + d) * H + c],     acc);
    acc2 = fmaf(qs[d + 1], Wk[(size_t)(h * HD + d + 1) * H + c], acc2);
  }
  qkpb[lh * H + c] = f2bf((acc + acc2) * RSQRT_HD);
}

// ---------------- K2: fused scorer MLP + scores via bf16 MFMA ----------------
// block = 256 thr (4 waves), M-tile = 64 tokens, K-chunk = 64, N-split waves:
// wave w owns W1 cols [w*64, w*64+64) and qkp cols [w*16, w*16+16).
__global__ __launch_bounds__(256) void k_fused(
    const float* __restrict__ te, const unsigned short* __restrict__ W1b,
    const float* __restrict__ b1, const float* __restrict__ W2,
    const float* __restrict__ b2, const unsigned short* __restrict__ qkpb,
    float* __restrict__ imp, float* __restrict__ sc) {
  // LDS map (bf16 tiles XOR-swizzled by ((row&7)<<4) on the byte offset):
  //   [0,      8192) te  [64][64]  bf16
  //   [8192,  40960) W1  [256][64] bf16
  //   [40960, 49152) qkp [64][64]  bf16
  //   [49152, 50176) b1s[256] f32; [50176,51200) w2s[256] f32
  //   [51200, 52480) red[64][5] f32; [52480, 52736) imp_lds[64]
  //   alias [0, 17152): sl f32 [64][67] score transpose buffer
  __shared__ __align__(16) char smem[52736];
  constexpr int W1_OFF = 8192, QK_OFF = 40960;
  const int tid  = threadIdx.x;
  const int lane = tid & 63;
  const int w    = tid >> 6;        // wave 0..3
  const int l15  = lane & 15;
  const int lk   = lane >> 4;       // k-group 0..3
  const int tok0 = blockIdx.x * 64;
  const int bb = tok0 >> 12;
  const int s0 = tok0 & (S - 1);

  float* b1s = (float*)(smem + 49152);
  float* w2s = (float*)(smem + 50176);
  float* red = (float*)(smem + 51200);
  float* impl = (float*)(smem + 52480);
  b1s[tid] = b1[tid];
  w2s[tid] = W2[tid];

  floatx4 acc1[4][4];
  floatx4 acc2[4];
#pragma unroll
  for (int mf = 0; mf < 4; mf++) {
#pragma unroll
    for (int nf = 0; nf < 4; nf++) acc1[mf][nf] = 0.f;
    acc2[mf] = 0.f;
  }

  for (int kk = 0; kk < H; kk += 64) {
    __syncthreads();  // previous iter's LDS reads done before overwrite
    // ---- stage te (fp32 -> bf16): 1024 float4 granules ----
#pragma unroll
    for (int i = 0; i < 4; i++) {
      int idx = tid + i * 256;
      int row = idx >> 4, k4 = idx & 15;
      float4 v = *(const float4*)(te + (size_t)(tok0 + row) * H + kk + k4 * 4);
      bhalf4 o;
      o.x = (short)f2bf(v.x); o.y = (short)f2bf(v.y);
      o.z = (short)f2bf(v.z); o.w = (short)f2bf(v.w);
      *(bhalf4*)(smem + ((row * 128 + k4 * 8) ^ ((row & 7) << 4))) = o;
    }
    // ---- stage W1 (bf16 direct): 2048 bhalf8 granules ----
#pragma unroll
    for (int i = 0; i < 8; i++) {
      int idx = tid + i * 256;
      int row = idx >> 3, k8 = idx & 7;
      bhalf8 v = *(const bhalf8*)(W1b + (size_t)row * H + kk + k8 * 8);
      *(bhalf8*)(smem + W1_OFF + ((row * 128 + k8 * 16) ^ ((row & 7) << 4))) = v;
    }
    // ---- stage qkp: 512 bhalf8 granules ----
#pragma unroll
    for (int i = 0; i < 2; i++) {
      int idx = tid + i * 256;
      int row = idx >> 3, k8 = idx & 7;
      bhalf8 v = *(const bhalf8*)(qkpb + (size_t)row * H + kk + k8 * 8);
      *(bhalf8*)(smem + QK_OFF + ((row * 128 + k8 * 16) ^ ((row & 7) << 4))) = v;
    }
    __syncthreads();
    // ---- MFMA: 2 k-steps of 32 ----
#pragma unroll
    for (int ks = 0; ks < 2; ks++) {
      bhalf8 a[4];
#pragma unroll
      for (int mf = 0; mf < 4; mf++) {
        int row = mf * 16 + l15;
        a[mf] = *(bhalf8*)(smem +
            ((row * 128 + (ks * 32 + lk * 8) * 2) ^ ((row & 7) << 4)));
      }
      bhalf8 b2f;
      {
        int j2 = w * 16 + l15;
        b2f = *(bhalf8*)(smem + QK_OFF +
            ((j2 * 128 + (ks * 32 + lk * 8) * 2) ^ ((j2 & 7) << 4)));
      }
#pragma unroll
      for (int nf = 0; nf < 4; nf++) {
        int j = w * 64 + nf * 16 + l15;
        bhalf8 bf = *(bhalf8*)(smem + W1_OFF +
            ((j * 128 + (ks * 32 + lk * 8) * 2) ^ ((j & 7) << 4)));
#pragma unroll
        for (int mf = 0; mf < 4; mf++)
          acc1[mf][nf] = __builtin_amdgcn_mfma_f32_16x16x32_bf16(
              a[mf], bf, acc1[mf][nf], 0, 0, 0);
      }
#pragma unroll
      for (int mf = 0; mf < 4; mf++)
        acc2[mf] = __builtin_amdgcn_mfma_f32_16x16x32_bf16(
            a[mf], b2f, acc2[mf], 0, 0, 0);
    }
  }

  // ---- epilogue: layer-2 partial per wave over its j-slice ----
  const float b2v = b2[0];
#pragma unroll
  for (int mf = 0; mf < 4; mf++) {
#pragma unroll
    for (int reg = 0; reg < 4; reg++) {
      float p = 0.f;
#pragma unroll
      for (int nf = 0; nf < 4; nf++) {
        int j = w * 64 + nf * 16 + l15;
        float x = acc1[mf][nf][reg] + b1s[j];
        p = fmaf(gelu_exact(x), w2s[j], p);
      }
      p += __shfl_xor(p, 1); p += __shfl_xor(p, 2);
      p += __shfl_xor(p, 4); p += __shfl_xor(p, 8);
      if (l15 == 0) red[(mf * 16 + lk * 4 + reg) * 5 + w] = p;
    }
  }
  __syncthreads();
  if (tid < 64) {
    float s = red[tid * 5 + 0] + red[tid * 5 + 1] + red[tid * 5 + 2] +
              red[tid * 5 + 3] + b2v;
    float im = 1.0f / (1.0f + expf(-s));
    impl[tid] = im;
    imp[tok0 + tid] = im;
  }
  __syncthreads();

  // ---- scale scores by imp and transpose via LDS ----
  float* sl = (float*)smem;   // [64 s][67]
#pragma unroll
  for (int mf = 0; mf < 4; mf++)
#pragma unroll
    for (int reg = 0; reg < 4; reg++) {
      int m = mf * 16 + lk * 4 + reg;
      int col = w * 16 + l15;
      sl[m * 67 + col] = acc2[mf][reg] * impl[m];
    }
  __syncthreads();
#pragma unroll
  for (int i = 0; i < 16; i++) {
    int idx = tid + i * 256;
    int lh = idx >> 6, s = idx & 63;
    sc[(size_t)(bb * LH + lh) * S + s0 + s] = sl[s * 67 + lh];
  }
}

// ------- K4: softmax over S per (b,l) for all 4 heads + mean over heads -------
__global__ __launch_bounds__(256) void k_softmax(float* __restrict__ sc,
                                                 float* __restrict__ aw) {
  const int tid = threadIdx.x;
  const int lane = tid & 63;
  const int h = tid >> 6;           // wave h handles head h's row
  const int b = blockIdx.x >> 4, l = blockIdx.x & 15;
  __shared__ __align__(16) float att4[4][S];   // 64 KB
  float4* row4 = (float4*)(sc + ((size_t)b * LH + h * NC + l) * S);
  float4 v[16];
  float m = -3.0e38f;
#pragma unroll
  for (int j = 0; j < 16; j++) {
    v[j] = row4[lane + j * 64];
    m = fmaxf(m, fmaxf(fmaxf(v[j].x, v[j].y), fmaxf(v[j].z, v[j].w)));
  }
#pragma unroll
  for (int off = 32; off; off >>= 1) m = fmaxf(m, __shfl_xor(m, off));
  float ssum = 0.f;
#pragma unroll
  for (int j = 0; j < 16; j++) {
    v[j].x = expf(v[j].x - m); v[j].y = expf(v[j].y - m);
    v[j].z = expf(v[j].z - m); v[j].w = expf(v[j].w - m);
    ssum += (v[j].x + v[j].y) + (v[j].z + v[j].w);
  }
#pragma unroll
  for (int off = 32; off; off >>= 1) ssum += __shfl_xor(ssum, off);
  const float inv = 1.0f / ssum;
  float4* a4 = (float4*)&att4[h][0];
#pragma unroll
  for (int j = 0; j < 16; j++) {
    v[j].x *= inv; v[j].y *= inv; v[j].z *= inv; v[j].w *= inv;
    row4[lane + j * 64] = v[j];
    a4[lane + j * 64] = v[j];
  }
  __syncthreads();
  float4* awb = (float4*)(aw + ((size_t)b * NC + l) * S);
#pragma unroll
  for (int i = 0; i < 4; i++) {
    int g = tid + i * 256;
    float4 a0 = ((float4*)&att4[0][0])[g];
    float4 a1 = ((float4*)&att4[1][0])[g];
    float4 a2 = ((float4*)&att4[2][0])[g];
    float4 a3 = ((float4*)&att4[3][0])[g];
    float4 o;
    o.x = (a0.x + a1.x + a2.x + a3.x) * 0.25f;
    o.y = (a0.y + a1.y + a2.y + a3.y) * 0.25f;
    o.z = (a0.z + a1.z + a2.z + a3.z) * 0.25f;
    o.w = (a0.w + a1.w + a2.w + a3.w) * 0.25f;
    awb[g] = o;
  }
}

// ---------------- K5: agg[b][lh][c] += sum_s attn[b][lh][s]*te[b][s][c] ----
__global__ __launch_bounds__(256) void k_agg(const float* __restrict__ attn,
                                             const float* __restrict__ te,
                                             float* __restrict__ agg) {
  __shared__ __align__(16) float at_sl[32][68];
  __shared__ __align__(16) float te_sl[32][128];
  const int tid = threadIdx.x;
  const int ji = tid & 31, ti = tid >> 5;
  const int cc = blockIdx.x;  // 8 chunks of 128 c
  const int sp = blockIdx.y;  // 8 splits of 512 s
  const int b = blockIdx.z;
  const int c0 = cc * 128;
  float acc[8][4];
#pragma unroll
  for (int t = 0; t < 8; t++)
#pragma unroll
    for (int g = 0; g < 4; g++) acc[t][g] = 0.f;

  for (int ss = sp * 512; ss < sp * 512 + 512; ss += 32) {
#pragma unroll
    for (int i = 0; i < 8; i++) {
      int idx = tid + i * 256;
      int lh = idx >> 5, s = idx & 31;
      at_sl[s][lh] = attn[(size_t)(b * LH + lh) * S + ss + s];
    }
#pragma unroll
    for (int i = 0; i < 16; i++) {
      int idx = tid + i * 256;
      int s = idx >> 7, c = idx & 127;
      te_sl[s][c] = te[(size_t)(b * S + ss + s) * H + c0 + c];
    }
    __syncthreads();
#pragma unroll 2
    for (int s = 0; s < 32; s++) {
      float4 a0 = ((const float4*)&at_sl[s][ti * 8])[0];
      float4 a1 = ((const float4*)&at_sl[s][ti * 8])[1];
      float a8[8] = {a0.x, a0.y, a0.z, a0.w, a1.x, a1.y, a1.z, a1.w};
      float t4[4];
#pragma unroll
      for (int g = 0; g < 4; g++) t4[g] = te_sl[s][ji + g * 32];
#pragma unroll
      for (int t = 0; t < 8; t++)
#pragma unroll
        for (int g = 0; g < 4; g++)
          acc[t][g] = fmaf(a8[t], t4[g], acc[t][g]);
    }
    __syncthreads();
  }
#pragma unroll
  for (int t = 0; t < 8; t++)
#pragma unroll
    for (int g = 0; g < 4; g++)
      atomicAdd(&agg[(size_t)(b * LH + ti * 8 + t) * H + c0 + ji + g * 32],
                acc[t][g]);
}

// ---------------- K6a: ctx[bl][h*HD+d] += Wv_h slice . agg ----------------
__global__ __launch_bounds__(256) void k_ctx(const float* __restrict__ agg,
                                             const float* __restrict__ Wv,
                                             float* __restrict__ ctx) {
  __shared__ __align__(16) float ag_sl[32][68];
  __shared__ float wv_sl[32][65];
  const int tid = threadIdx.x;
  const int ji = tid & 31, ti = tid >> 5;
  const int h = blockIdx.x >> 1;        // 4 heads
  const int blh = blockIdx.x & 1;       // bl-half
  const int dc = blockIdx.y;            // 4 chunks of 64 d
  const int cs = blockIdx.z;            // 4 splits of 256 c
  float acc[8][2];
#pragma unroll
  for (int m = 0; m < 8; m++) { acc[m][0] = 0.f; acc[m][1] = 0.f; }

  for (int sl = 0; sl < 256; sl += 32) {
#pragma unroll
    for (int i = 0; i < 8; i++) {
      int idx = tid + i * 256;
      int bl_l = idx >> 5, c = idx & 31;
      int bl = blh * 64 + bl_l;
      int row = (bl >> 4) * LH + h * NC + (bl & 15);
      ag_sl[c][bl_l] = agg[(size_t)row * H + cs * 256 + sl + c];
    }
#pragma unroll
    for (int i = 0; i < 8; i++) {
      int idx = tid + i * 256;
      int d = idx >> 5, c = idx & 31;
      wv_sl[c][d] = Wv[(size_t)(h * HD + dc * 64 + d) * H + cs * 256 + sl + c];
    }
    __syncthreads();
#pragma unroll 2
    for (int c = 0; c < 32; c++) {
      float am[8];
#pragma unroll
      for (int g = 0; g < 2; g++) {
        float4 a = ((const float4*)&ag_sl[c][ti * 8])[g];
        am[g * 4 + 0] = a.x; am[g * 4 + 1] = a.y;
        am[g * 4 + 2] = a.z; am[g * 4 + 3] = a.w;
      }
      float w0 = wv_sl[c][ji], w1 = wv_sl[c][ji + 32];
#pragma unroll
      for (int m = 0; m < 8; m++) {
        acc[m][0] = fmaf(am[m], w0, acc[m][0]);
        acc[m][1] = fmaf(am[m], w1, acc[m][1]);
      }
    }
    __syncthreads();
  }
#pragma unroll
  for (int m = 0; m < 8; m++) {
    int bl = blh * 64 + ti * 8 + m;
    atomicAdd(&ctx[(size_t)bl * H + h * HD + dc * 64 + ji], acc[m][0]);
    atomicAdd(&ctx[(size_t)bl * H + h * HD + dc * 64 + ji + 32], acc[m][1]);
  }
}

// ---------------- K6b: outp[bl][o] += Wo[o] . (ctx[bl]+bv) ----------------
__global__ __launch_bounds__(256) void k_out(const float* __restrict__ ctx,
                                             const float* __restrict__ bv,
                                             const float* __restrict__ Wo,
                                             float* __restrict__ outp) {
  __shared__ __align__(16) float cx_sl[32][68];
  __shared__ float wo_sl[32][65];
  const int tid = threadIdx.x;
  const int ji = tid & 31, ti = tid >> 5;
  const int oc = blockIdx.x;            // 16 chunks of 64 o
  const int is = blockIdx.y;            // 4 splits of 256 i
  const int blh = blockIdx.z;           // bl-half
  float acc[8][2];
#pragma unroll
  for (int m = 0; m < 8; m++) { acc[m][0] = 0.f; acc[m][1] = 0.f; }

  for (int sl = 0; sl < 256; sl += 32) {
#pragma unroll
    for (int i = 0; i < 8; i++) {
      int idx = tid + i * 256;
      int bl_l = idx >> 5, ii = idx & 31;
      int gi = is * 256 + sl + ii;
      cx_sl[ii][bl_l] = ctx[(size_t)(blh * 64 + bl_l) * H + gi] + bv[gi];
    }
#pragma unroll
    for (int i = 0; i < 8; i++) {
      int idx = tid + i * 256;
      int o = idx >> 5, ii = idx & 31;
      wo_sl[ii][o] = Wo[(size_t)(oc * 64 + o) * H + is * 256 + sl + ii];
    }
    __syncthreads();
#pragma unroll 2
    for (int c = 0; c < 32; c++) {
      float am[8];
#pragma unroll
      for (int g = 0; g < 2; g++) {
        float4 a = ((const float4*)&cx_sl[c][ti * 8])[g];
        am[g * 4 + 0] = a.x; am[g * 4 + 1] = a.y;
        am[g * 4 + 2] = a.z; am[g * 4 + 3] = a.w;
      }
      float w0 = wo_sl[c][ji], w1 = wo_sl[c][ji + 32];
#pragma unroll
      for (int m = 0; m < 8; m++) {
        acc[m][0] = fmaf(am[m], w0, acc[m][0]);
        acc[m][1] = fmaf(am[m], w1, acc[m][1]);
      }
    }
    __syncthreads();
  }
#pragma unroll
  for (int m = 0; m < 8; m++) {
    int bl = blh * 64 + ti * 8 + m;
    atomicAdd(&outp[(size_t)bl * H + oc * 64 + ji], acc[m][0]);
    atomicAdd(&outp[(size_t)bl * H + oc * 64 + ji + 32], acc[m][1]);
  }
}

// ---------------- K6c: RMSNorm -> compressed ----------------
__global__ __launch_bounds__(256) void k_rms(const float* __restrict__ outp,
                                             const float* __restrict__ bo,
                                             const float* __restrict__ rw,
                                             float* __restrict__ comp) {
  const int tid = threadIdx.x;
  const int bl = blockIdx.x;
  __shared__ float red[4];
  float4 v = ((const float4*)(outp + (size_t)bl * H))[tid];
  float4 bb = ((const float4*)bo)[tid];
  v.x += bb.x; v.y += bb.y; v.z += bb.z; v.w += bb.w;
  float ss = v.x * v.x + v.y * v.y + v.z * v.z + v.w * v.w;
#pragma unroll
  for (int off = 32; off; off >>= 1) ss += __shfl_xor(ss, off);
  if ((tid & 63) == 0) red[tid >> 6] = ss;
  __syncthreads();
  ss = (red[0] + red[1]) + (red[2] + red[3]);
  const float rms = sqrtf(ss * (1.0f / H) + REPS);
  const float inv = 1.0f / rms;
  float4 w = ((const float4*)rw)[tid];
  float4 o;
  o.x = v.x * inv * w.x; o.y = v.y * inv * w.y;
  o.z = v.z * inv * w.z; o.w = v.w * inv * w.w;
  ((float4*)(comp + (size_t)bl * H))[tid] = o;
}

}  // namespace

extern "C" void kernel_launch(void* const* d_in, const int* in_sizes, int n_in,
                              void* d_out, int out_size, void* d_ws,
                              size_t ws_size, hipStream_t stream) {
  (void)in_sizes; (void)n_in; (void)out_size; (void)ws_size;
  const float* te   = (const float*)d_in[0];
  const float* W1   = (const float*)d_in[1];
  const float* b1   = (const float*)d_in[2];
  const float* W2   = (const float*)d_in[3];
  const float* b2   = (const float*)d_in[4];
  const float* cq   = (const float*)d_in[5];
  const float* Wq   = (const float*)d_in[6];
  const float* bq   = (const float*)d_in[7];
  const float* Wk   = (const float*)d_in[8];
  // d_in[9] = bk: constant over s -> softmax-invariant, dropped
  const float* Wv   = (const float*)d_in[10];
  const float* bv   = (const float*)d_in[11];
  const float* Wo   = (const float*)d_in[12];
  const float* bo   = (const float*)d_in[13];
  const float* rmsw = (const float*)d_in[14];

  float* out_comp = (float*)d_out;              // [B][NC][H]   = 131072
  float* out_imp  = out_comp + B * NC * H;      // [B][S]       =  32768
  float* out_attw = out_imp + B * S;            // [B][NC][S]   = 524288

  float* q    = (float*)d_ws;                   //  16384 f
  float* qkp_region = q + NC * H;               //  65536 f slot (ushort qkp uses half)
  unsigned short* qkpb = (unsigned short*)qkp_region;
  float* sc   = qkp_region + LH * H;            // 2097152 f (scores/attn)
  float* agg  = sc + (size_t)B * LH * S;        //  524288 f (atomic, zeroed)
  float* ctx  = agg + (size_t)B * LH * H;       //  131072 f (atomic, zeroed)
  float* outp = ctx + (size_t)B * NC * H;       //  131072 f (atomic, zeroed)
  unsigned short* W1b = (unsigned short*)(outp + B * NC * H);  // 262144 us

  hipMemsetAsync(agg, 0, (size_t)(B * LH * H + 2 * B * NC * H) * sizeof(float),
                 stream);

  k_prep<<<256, 256, 0, stream>>>(W1, W1b);
  k_q<<<dim3(NC, 8), 256, 0, stream>>>(cq, Wq, bq, q);
  k_qkproj<<<dim3(LH, H / 256), 256, 0, stream>>>(q, Wk, qkpb);
  k_fused<<<B * S / 64, 256, 0, stream>>>(te, W1b, b1, W2, b2, qkpb,
                                          out_imp, sc);
  k_softmax<<<B * NC, 256, 0, stream>>>(sc, out_attw);
  k_agg<<<dim3(8, 8, 8), 256, 0, stream>>>(sc, te, agg);
  k_ctx<<<dim3(8, 4, 4), 256, 0, stream>>>(agg, Wv, ctx);
  k_out<<<dim3(16, 4, 2), 256, 0, stream>>>(ctx, bv, Wo, outp);
  k_rms<<<B * NC, 256, 0, stream>>>(outp, bo, rmsw, out_comp);
}

// Round 4
// 404.573 us; speedup vs baseline: 1.9826x; 1.1013x over previous
//
#include <hip/hip_runtime.h>
#include <math.h>

namespace {

constexpr int B  = 8;
constexpr int S  = 4096;
constexpr int H  = 1024;
constexpr int NC = 16;
constexpr int NH = 4;
constexpr int HD = 256;
constexpr int LH = NH * NC;      // 64 score rows per batch, lh = h*NC + l
constexpr float RSQRT_HD = 0.0625f;   // 1/sqrt(256)
constexpr float REPS = 1e-6f;

typedef __attribute__((ext_vector_type(8))) short bhalf8;
typedef __attribute__((ext_vector_type(4))) short bhalf4;
typedef __attribute__((ext_vector_type(4))) float floatx4;

__device__ __forceinline__ unsigned short f2bf(float f) {
  unsigned u = __builtin_bit_cast(unsigned, f);
  u += 0x7fffu + ((u >> 16) & 1u);          // RNE
  return (unsigned short)(u >> 16);
}

__device__ __forceinline__ float gelu_exact(float x) {
  return 0.5f * x * (1.0f + erff(x * 0.70710678118654752440f));
}

// ---------------- K_prep: W1 fp32 -> bf16 copy ----------------
__global__ __launch_bounds__(256) void k_prep(const float* __restrict__ W1,
                                              unsigned short* __restrict__ W1b) {
  int i = blockIdx.x * 256 + threadIdx.x;   // float4 granule; 65536 total
  float4 v = ((const float4*)W1)[i];
  bhalf4 o;
  o.x = (short)f2bf(v.x); o.y = (short)f2bf(v.y);
  o.z = (short)f2bf(v.z); o.w = (short)f2bf(v.w);
  ((bhalf4*)W1b)[i] = o;
}

// ---------------- K0: q[l][o] = cq[l] . Wq[o] + bq[o] ----------------
__global__ __launch_bounds__(256) void k_q(const float* __restrict__ cq,
                                           const float* __restrict__ Wq,
                                           const float* __restrict__ bq,
                                           float* __restrict__ q) {
  const int l = blockIdx.x;
  const int oc = blockIdx.y;                // 8 chunks of 128 o
  const int lane = threadIdx.x & 63;
  const int w = threadIdx.x >> 6;
  __shared__ __align__(16) float cqs[H];
  for (int i = threadIdx.x; i < H; i += 256) cqs[i] = cq[l * H + i];
  __syncthreads();
  float4 c4[4];
#pragma unroll
  for (int j = 0; j < 4; j++) c4[j] = ((const float4*)cqs)[lane * 4 + j];
  for (int oo = 0; oo < 32; oo++) {
    int o = oc * 128 + w * 32 + oo;
    const float4* wr = (const float4*)(Wq + (size_t)o * H) + lane * 4;
    float p = 0.f;
#pragma unroll
    for (int j = 0; j < 4; j++) {
      float4 wv = wr[j];
      p = fmaf(wv.x, c4[j].x, p); p = fmaf(wv.y, c4[j].y, p);
      p = fmaf(wv.z, c4[j].z, p); p = fmaf(wv.w, c4[j].w, p);
    }
#pragma unroll
    for (int off = 32; off; off >>= 1) p += __shfl_xor(p, off);
    if (lane == 0) q[l * H + o] = p + bq[o];
  }
}

// -------- K1: qkp[lh][c] = bf16( (1/sqrt(HD)) * q_head . Wk_head[:,c] )
// wave w covers d in [w*64, w*64+64); lane covers one c of 64
__global__ __launch_bounds__(256) void k_qkproj(const float* __restrict__ q,
                                                const float* __restrict__ Wk,
                                                unsigned short* __restrict__ qkpb) {
  const int lh = blockIdx.x;            // lh = h*NC + l
  const int h = lh >> 4, l = lh & 15;
  const int c0 = blockIdx.y * 64;
  const int tid = threadIdx.x;
  const int lane = tid & 63;
  const int w = tid >> 6;
  __shared__ float qs[HD];
  __shared__ float part[4][64];
  if (tid < HD) qs[tid] = q[l * H + h * HD + tid];
  __syncthreads();
  float acc = 0.f, acc2 = 0.f;
#pragma unroll 8
  for (int dd = 0; dd < 64; dd += 2) {
    int d = w * 64 + dd;
    acc  = fmaf(qs[d],     Wk[(size_t)(h * HD + d) * H + c0 + lane],     acc);
    acc2 = fmaf(qs[d + 1], Wk[(size_t)(h * HD + d + 1) * H + c0 + lane], acc2);
  }
  part[w][lane] = acc + acc2;
  __syncthreads();
  if (tid < 64) {
    float s = part[0][tid] + part[1][tid] + part[2][tid] + part[3][tid];
    qkpb[lh * H + c0 + tid] = f2bf(s * RSQRT_HD);
  }
}

// ---------------- K2: fused scorer MLP + scores via bf16 MFMA ----------------
// block = 256 thr (4 waves), M-tile = 64 tokens, K-chunk = 64.
// LDS stages ONLY the te tile; B-fragments (W1b, qkpb) read direct from
// global (L2-resident, already contiguous 16B per fragment).
// N-split: wave w owns W1 cols [w*64,+64) and qkp cols [w*16,+16).
__global__ __launch_bounds__(256, 3) void k_fused(
    const float* __restrict__ te, const unsigned short* __restrict__ W1b,
    const float* __restrict__ b1, const float* __restrict__ W2,
    const float* __restrict__ b2, const unsigned short* __restrict__ qkpb,
    float* __restrict__ imp, float* __restrict__ sc) {
  // LDS: [0,8192) te tile [64][64] bf16 swz ^((row&7)<<4)
  //      alias [0,17152) sl f32 [64][67] (epilogue transpose)
  //      [17408,18432) b1s; [18432,19456) w2s; [19456,20736) red[64][5];
  //      [20736,20992) impl[64]
  __shared__ __align__(16) char smem[20992];
  const int tid  = threadIdx.x;
  const int lane = tid & 63;
  const int w    = tid >> 6;
  const int l15  = lane & 15;
  const int lk   = lane >> 4;
  const int tok0 = blockIdx.x * 64;
  const int bb = tok0 >> 12;
  const int s0 = tok0 & (S - 1);

  float* b1s  = (float*)(smem + 17408);
  float* w2s  = (float*)(smem + 18432);
  float* red  = (float*)(smem + 19456);
  float* impl = (float*)(smem + 20736);
  b1s[tid] = b1[tid];
  w2s[tid] = W2[tid];

  floatx4 acc1[4][4];
  floatx4 acc2[4];
#pragma unroll
  for (int mf = 0; mf < 4; mf++) {
#pragma unroll
    for (int nf = 0; nf < 4; nf++) acc1[mf][nf] = 0.f;
    acc2[mf] = 0.f;
  }

  const unsigned short* w1base = W1b + (size_t)(w * 64 + l15) * H + lk * 8;
  const unsigned short* qkbase = qkpb + (size_t)(w * 16 + l15) * H + lk * 8;

  for (int kk = 0; kk < H; kk += 64) {
    __syncthreads();
    // ---- stage te (fp32 -> bf16): 1024 bhalf4 granules ----
#pragma unroll
    for (int i = 0; i < 4; i++) {
      int idx = tid + i * 256;
      int row = idx >> 4, k4 = idx & 15;
      float4 v = *(const float4*)(te + (size_t)(tok0 + row) * H + kk + k4 * 4);
      bhalf4 o;
      o.x = (short)f2bf(v.x); o.y = (short)f2bf(v.y);
      o.z = (short)f2bf(v.z); o.w = (short)f2bf(v.w);
      *(bhalf4*)(smem + ((row * 128 + k4 * 8) ^ ((row & 7) << 4))) = o;
    }
    __syncthreads();
    // ---- MFMA: 2 k-steps of 32; B-frags direct from global ----
#pragma unroll
    for (int ks = 0; ks < 2; ks++) {
      bhalf8 a[4];
#pragma unroll
      for (int mf = 0; mf < 4; mf++) {
        int row = mf * 16 + l15;
        a[mf] = *(bhalf8*)(smem +
            ((row * 128 + (ks * 32 + lk * 8) * 2) ^ ((row & 7) << 4)));
      }
      bhalf8 bq8 = *(const bhalf8*)(qkbase + kk + ks * 32);
#pragma unroll
      for (int nf = 0; nf < 4; nf++) {
        bhalf8 bf = *(const bhalf8*)(w1base + (size_t)nf * 16 * H + kk + ks * 32);
#pragma unroll
        for (int mf = 0; mf < 4; mf++)
          acc1[mf][nf] = __builtin_amdgcn_mfma_f32_16x16x32_bf16(
              a[mf], bf, acc1[mf][nf], 0, 0, 0);
      }
#pragma unroll
      for (int mf = 0; mf < 4; mf++)
        acc2[mf] = __builtin_amdgcn_mfma_f32_16x16x32_bf16(
            a[mf], bq8, acc2[mf], 0, 0, 0);
    }
  }

  // ---- epilogue: layer-2 partial per wave over its j-slice ----
  const float b2v = b2[0];
#pragma unroll
  for (int mf = 0; mf < 4; mf++) {
#pragma unroll
    for (int reg = 0; reg < 4; reg++) {
      float p = 0.f;
#pragma unroll
      for (int nf = 0; nf < 4; nf++) {
        int j = w * 64 + nf * 16 + l15;
        float x = acc1[mf][nf][reg] + b1s[j];
        p = fmaf(gelu_exact(x), w2s[j], p);
      }
      p += __shfl_xor(p, 1); p += __shfl_xor(p, 2);
      p += __shfl_xor(p, 4); p += __shfl_xor(p, 8);
      if (l15 == 0) red[(mf * 16 + lk * 4 + reg) * 5 + w] = p;
    }
  }
  __syncthreads();
  if (tid < 64) {
    float s = red[tid * 5 + 0] + red[tid * 5 + 1] + red[tid * 5 + 2] +
              red[tid * 5 + 3] + b2v;
    float im = 1.0f / (1.0f + expf(-s));
    impl[tid] = im;
    imp[tok0 + tid] = im;
  }
  __syncthreads();

  // ---- scale scores by imp and transpose via LDS ----
  float* sl = (float*)smem;   // [64 s][67]
#pragma unroll
  for (int mf = 0; mf < 4; mf++)
#pragma unroll
    for (int reg = 0; reg < 4; reg++) {
      int m = mf * 16 + lk * 4 + reg;
      int col = w * 16 + l15;
      sl[m * 67 + col] = acc2[mf][reg] * impl[m];
    }
  __syncthreads();
#pragma unroll
  for (int i = 0; i < 16; i++) {
    int idx = tid + i * 256;
    int lh = idx >> 6, s = idx & 63;
    sc[(size_t)(bb * LH + lh) * S + s0 + s] = sl[s * 67 + lh];
  }
}

// ------- K4: softmax over S per (b,l) for all 4 heads + mean over heads -------
__global__ __launch_bounds__(256) void k_softmax(float* __restrict__ sc,
                                                 float* __restrict__ aw) {
  const int tid = threadIdx.x;
  const int lane = tid & 63;
  const int h = tid >> 6;           // wave h handles head h's row
  const int b = blockIdx.x >> 4, l = blockIdx.x & 15;
  __shared__ __align__(16) float att4[4][S];   // 64 KB
  float4* row4 = (float4*)(sc + ((size_t)b * LH + h * NC + l) * S);
  float4 v[16];
  float m = -3.0e38f;
#pragma unroll
  for (int j = 0; j < 16; j++) {
    v[j] = row4[lane + j * 64];
    m = fmaxf(m, fmaxf(fmaxf(v[j].x, v[j].y), fmaxf(v[j].z, v[j].w)));
  }
#pragma unroll
  for (int off = 32; off; off >>= 1) m = fmaxf(m, __shfl_xor(m, off));
  float ssum = 0.f;
#pragma unroll
  for (int j = 0; j < 16; j++) {
    v[j].x = expf(v[j].x - m); v[j].y = expf(v[j].y - m);
    v[j].z = expf(v[j].z - m); v[j].w = expf(v[j].w - m);
    ssum += (v[j].x + v[j].y) + (v[j].z + v[j].w);
  }
#pragma unroll
  for (int off = 32; off; off >>= 1) ssum += __shfl_xor(ssum, off);
  const float inv = 1.0f / ssum;
  float4* a4 = (float4*)&att4[h][0];
#pragma unroll
  for (int j = 0; j < 16; j++) {
    v[j].x *= inv; v[j].y *= inv; v[j].z *= inv; v[j].w *= inv;
    row4[lane + j * 64] = v[j];
    a4[lane + j * 64] = v[j];
  }
  __syncthreads();
  float4* awb = (float4*)(aw + ((size_t)b * NC + l) * S);
#pragma unroll
  for (int i = 0; i < 4; i++) {
    int g = tid + i * 256;
    float4 a0 = ((float4*)&att4[0][0])[g];
    float4 a1 = ((float4*)&att4[1][0])[g];
    float4 a2 = ((float4*)&att4[2][0])[g];
    float4 a3 = ((float4*)&att4[3][0])[g];
    float4 o;
    o.x = (a0.x + a1.x + a2.x + a3.x) * 0.25f;
    o.y = (a0.y + a1.y + a2.y + a3.y) * 0.25f;
    o.z = (a0.z + a1.z + a2.z + a3.z) * 0.25f;
    o.w = (a0.w + a1.w + a2.w + a3.w) * 0.25f;
    awb[g] = o;
  }
}

// ------- K5: agg[b][lh][c] += sum_s attn[b][lh][s]*te[b][s][c]  (bf16 MFMA)
// grid (4 nb, 8 ksplit, 8 b): block = M=64 lh x N=256 c, K=512 s.
// A tile [64 lh][64 s] bf16 (swz ^((lh&7)<<4)); B tile = te TRANSPOSED during
// staging: Bt[c][s] bf16, s-pairs packed in b32 writes, swz ^(((c>>2)&7)<<4).
__global__ __launch_bounds__(256) void k_agg(const float* __restrict__ attn,
                                             const float* __restrict__ te,
                                             float* __restrict__ agg) {
  __shared__ __align__(16) char smem[40960];  // A 8KB @0, Bt 32KB @8192
  const int tid = threadIdx.x;
  const int lane = tid & 63;
  const int w = tid >> 6;
  const int l15 = lane & 15;
  const int lk = lane >> 4;
  const int c0 = blockIdx.x * 256;
  const int sbase = blockIdx.y * 512;
  const int b = blockIdx.z;

  floatx4 acc[4][4];
#pragma unroll
  for (int mf = 0; mf < 4; mf++)
#pragma unroll
    for (int nf = 0; nf < 4; nf++) acc[mf][nf] = 0.f;

  for (int ss = sbase; ss < sbase + 512; ss += 64) {
    __syncthreads();
    // ---- stage A: attn[lh][ss..+64] fp32 -> bf16, 1024 bhalf4 granules ----
#pragma unroll
    for (int i = 0; i < 4; i++) {
      int idx = tid + i * 256;
      int lh = idx >> 4, s4 = idx & 15;
      float4 v = *(const float4*)(attn + (size_t)(b * LH + lh) * S + ss + s4 * 4);
      bhalf4 o;
      o.x = (short)f2bf(v.x); o.y = (short)f2bf(v.y);
      o.z = (short)f2bf(v.z); o.w = (short)f2bf(v.w);
      *(bhalf4*)(smem + ((lh * 128 + s4 * 8) ^ ((lh & 7) << 4))) = o;
    }
    // ---- stage Bt: te[s][c] -> Bt[c][s], s-pair packed b32 writes ----
#pragma unroll
    for (int i = 0; i < 8; i++) {
      int idx = tid + i * 256;
      int c4 = idx & 63, sp = idx >> 6;     // sp in 0..31
      int s = ss + sp * 2;
      float4 v0 = *(const float4*)(te + (size_t)(b * S + s) * H + c0 + c4 * 4);
      float4 v1 = *(const float4*)(te + (size_t)(b * S + s + 1) * H + c0 + c4 * 4);
      float a0[4], a1[4];
      *(float4*)a0 = v0; *(float4*)a1 = v1;
      const int swz = (c4 & 7) << 4;        // (c>>2)&7 == c4&7 for j<4
#pragma unroll
      for (int j = 0; j < 4; j++) {
        int c = c4 * 4 + j;
        unsigned pk = (unsigned)f2bf(a0[j]) | ((unsigned)f2bf(a1[j]) << 16);
        *(unsigned*)(smem + 8192 + ((c * 128 + sp * 4) ^ swz)) = pk;
      }
    }
    __syncthreads();
    // ---- MFMA: 2 k-steps of 32 ----
#pragma unroll
    for (int ks = 0; ks < 2; ks++) {
      bhalf8 a[4];
#pragma unroll
      for (int mf = 0; mf < 4; mf++) {
        int row = mf * 16 + l15;
        a[mf] = *(bhalf8*)(smem +
            ((row * 128 + (ks * 32 + lk * 8) * 2) ^ ((row & 7) << 4)));
      }
#pragma unroll
      for (int nf = 0; nf < 4; nf++) {
        int c = w * 64 + nf * 16 + l15;
        bhalf8 bf = *(bhalf8*)(smem + 8192 +
            ((c * 128 + (ks * 32 + lk * 8) * 2) ^ (((c >> 2) & 7) << 4)));
#pragma unroll
        for (int mf = 0; mf < 4; mf++)
          acc[mf][nf] = __builtin_amdgcn_mfma_f32_16x16x32_bf16(
              a[mf], bf, acc[mf][nf], 0, 0, 0);
      }
    }
  }
#pragma unroll
  for (int mf = 0; mf < 4; mf++)
#pragma unroll
    for (int nf = 0; nf < 4; nf++)
#pragma unroll
      for (int r = 0; r < 4; r++) {
        int lh = mf * 16 + lk * 4 + r;
        int c = c0 + w * 64 + nf * 16 + l15;
        atomicAdd(&agg[(size_t)(b * LH + lh) * H + c], acc[mf][nf][r]);
      }
}

// ---------------- K6a: ctx[bl][h*HD+d] += Wv_h slice . agg ----------------
__global__ __launch_bounds__(256) void k_ctx(const float* __restrict__ agg,
                                             const float* __restrict__ Wv,
                                             float* __restrict__ ctx) {
  __shared__ __align__(16) float ag_sl[32][68];
  __shared__ float wv_sl[32][65];
  const int tid = threadIdx.x;
  const int ji = tid & 31, ti = tid >> 5;
  const int h = blockIdx.x >> 1;        // 4 heads
  const int blh = blockIdx.x & 1;       // bl-half
  const int dc = blockIdx.y;            // 4 chunks of 64 d
  const int cs = blockIdx.z;            // 4 splits of 256 c
  float acc[8][2];
#pragma unroll
  for (int m = 0; m < 8; m++) { acc[m][0] = 0.f; acc[m][1] = 0.f; }

  for (int sl = 0; sl < 256; sl += 32) {
#pragma unroll
    for (int i = 0; i < 8; i++) {
      int idx = tid + i * 256;
      int bl_l = idx >> 5, c = idx & 31;
      int bl = blh * 64 + bl_l;
      int row = (bl >> 4) * LH + h * NC + (bl & 15);
      ag_sl[c][bl_l] = agg[(size_t)row * H + cs * 256 + sl + c];
    }
#pragma unroll
    for (int i = 0; i < 8; i++) {
      int idx = tid + i * 256;
      int d = idx >> 5, c = idx & 31;
      wv_sl[c][d] = Wv[(size_t)(h * HD + dc * 64 + d) * H + cs * 256 + sl + c];
    }
    __syncthreads();
#pragma unroll 2
    for (int c = 0; c < 32; c++) {
      float am[8];
#pragma unroll
      for (int g = 0; g < 2; g++) {
        float4 a = ((const float4*)&ag_sl[c][ti * 8])[g];
        am[g * 4 + 0] = a.x; am[g * 4 + 1] = a.y;
        am[g * 4 + 2] = a.z; am[g * 4 + 3] = a.w;
      }
      float w0 = wv_sl[c][ji], w1 = wv_sl[c][ji + 32];
#pragma unroll
      for (int m = 0; m < 8; m++) {
        acc[m][0] = fmaf(am[m], w0, acc[m][0]);
        acc[m][1] = fmaf(am[m], w1, acc[m][1]);
      }
    }
    __syncthreads();
  }
#pragma unroll
  for (int m = 0; m < 8; m++) {
    int bl = blh * 64 + ti * 8 + m;
    atomicAdd(&ctx[(size_t)bl * H + h * HD + dc * 64 + ji], acc[m][0]);
    atomicAdd(&ctx[(size_t)bl * H + h * HD + dc * 64 + ji + 32], acc[m][1]);
  }
}

// ---------------- K6b: outp[bl][o] += Wo[o] . (ctx[bl]+bv) ----------------
__global__ __launch_bounds__(256) void k_out(const float* __restrict__ ctx,
                                             const float* __restrict__ bv,
                                             const float* __restrict__ Wo,
                                             float* __restrict__ outp) {
  __shared__ __align__(16) float cx_sl[32][68];
  __shared__ float wo_sl[32][65];
  const int tid = threadIdx.x;
  const int ji = tid & 31, ti = tid >> 5;
  const int oc = blockIdx.x;            // 16 chunks of 64 o
  const int is = blockIdx.y;            // 4 splits of 256 i
  const int blh = blockIdx.z;           // bl-half
  float acc[8][2];
#pragma unroll
  for (int m = 0; m < 8; m++) { acc[m][0] = 0.f; acc[m][1] = 0.f; }

  for (int sl = 0; sl < 256; sl += 32) {
#pragma unroll
    for (int i = 0; i < 8; i++) {
      int idx = tid + i * 256;
      int bl_l = idx >> 5, ii = idx & 31;
      int gi = is * 256 + sl + ii;
      cx_sl[ii][bl_l] = ctx[(size_t)(blh * 64 + bl_l) * H + gi] + bv[gi];
    }
#pragma unroll
    for (int i = 0; i < 8; i++) {
      int idx = tid + i * 256;
      int o = idx >> 5, ii = idx & 31;
      wo_sl[ii][o] = Wo[(size_t)(oc * 64 + o) * H + is * 256 + sl + ii];
    }
    __syncthreads();
#pragma unroll 2
    for (int c = 0; c < 32; c++) {
      float am[8];
#pragma unroll
      for (int g = 0; g < 2; g++) {
        float4 a = ((const float4*)&cx_sl[c][ti * 8])[g];
        am[g * 4 + 0] = a.x; am[g * 4 + 1] = a.y;
        am[g * 4 + 2] = a.z; am[g * 4 + 3] = a.w;
      }
      float w0 = wo_sl[c][ji], w1 = wo_sl[c][ji + 32];
#pragma unroll
      for (int m = 0; m < 8; m++) {
        acc[m][0] = fmaf(am[m], w0, acc[m][0]);
        acc[m][1] = fmaf(am[m], w1, acc[m][1]);
      }
    }
    __syncthreads();
  }
#pragma unroll
  for (int m = 0; m < 8; m++) {
    int bl = blh * 64 + ti * 8 + m;
    atomicAdd(&outp[(size_t)bl * H + oc * 64 + ji], acc[m][0]);
    atomicAdd(&outp[(size_t)bl * H + oc * 64 + ji + 32], acc[m][1]);
  }
}

// ---------------- K6c: RMSNorm -> compressed ----------------
__global__ __launch_bounds__(256) void k_rms(const float* __restrict__ outp,
                                             const float* __restrict__ bo,
                                             const float* __restrict__ rw,
                                             float* __restrict__ comp) {
  const int tid = threadIdx.x;
  const int bl = blockIdx.x;
  __shared__ float red[4];
  float4 v = ((const float4*)(outp + (size_t)bl * H))[tid];
  float4 bb = ((const float4*)bo)[tid];
  v.x += bb.x; v.y += bb.y; v.z += bb.z; v.w += bb.w;
  float ss = v.x * v.x + v.y * v.y + v.z * v.z + v.w * v.w;
#pragma unroll
  for (int off = 32; off; off >>= 1) ss += __shfl_xor(ss, off);
  if ((tid & 63) == 0) red[tid >> 6] = ss;
  __syncthreads();
  ss = (red[0] + red[1]) + (red[2] + red[3]);
  const float rms = sqrtf(ss * (1.0f / H) + REPS);
  const float inv = 1.0f / rms;
  float4 w = ((const float4*)rw)[tid];
  float4 o;
  o.x = v.x * inv * w.x; o.y = v.y * inv * w.y;
  o.z = v.z * inv * w.z; o.w = v.w * inv * w.w;
  ((float4*)(comp + (size_t)bl * H))[tid] = o;
}

}  // namespace

extern "C" void kernel_launch(void* const* d_in, const int* in_sizes, int n_in,
                              void* d_out, int out_size, void* d_ws,
                              size_t ws_size, hipStream_t stream) {
  (void)in_sizes; (void)n_in; (void)out_size; (void)ws_size;
  const float* te   = (const float*)d_in[0];
  const float* W1   = (const float*)d_in[1];
  const float* b1   = (const float*)d_in[2];
  const float* W2   = (const float*)d_in[3];
  const float* b2   = (const float*)d_in[4];
  const float* cq   = (const float*)d_in[5];
  const float* Wq   = (const float*)d_in[6];
  const float* bq   = (const float*)d_in[7];
  const float* Wk   = (const float*)d_in[8];
  // d_in[9] = bk: constant over s -> softmax-invariant, dropped
  const float* Wv   = (const float*)d_in[10];
  const float* bv   = (const float*)d_in[11];
  const float* Wo   = (const float*)d_in[12];
  const float* bo   = (const float*)d_in[13];
  const float* rmsw = (const float*)d_in[14];

  float* out_comp = (float*)d_out;              // [B][NC][H]   = 131072
  float* out_imp  = out_comp + B * NC * H;      // [B][S]       =  32768
  float* out_attw = out_imp + B * S;            // [B][NC][S]   = 524288

  float* q    = (float*)d_ws;                   //  16384 f
  float* qkp_region = q + NC * H;               //  65536 f slot (ushort qkp uses half)
  unsigned short* qkpb = (unsigned short*)qkp_region;
  float* sc   = qkp_region + LH * H;            // 2097152 f (scores/attn)
  float* agg  = sc + (size_t)B * LH * S;        //  524288 f (atomic, zeroed)
  float* ctx  = agg + (size_t)B * LH * H;       //  131072 f (atomic, zeroed)
  float* outp = ctx + (size_t)B * NC * H;       //  131072 f (atomic, zeroed)
  unsigned short* W1b = (unsigned short*)(outp + B * NC * H);  // 262144 us

  hipMemsetAsync(agg, 0, (size_t)(B * LH * H + 2 * B * NC * H) * sizeof(float),
                 stream);

  k_prep<<<256, 256, 0, stream>>>(W1, W1b);
  k_q<<<dim3(NC, 8), 256, 0, stream>>>(cq, Wq, bq, q);
  k_qkproj<<<dim3(LH, 16), 256, 0, stream>>>(q, Wk, qkpb);
  k_fused<<<B * S / 64, 256, 0, stream>>>(te, W1b, b1, W2, b2, qkpb,
                                          out_imp, sc);
  k_softmax<<<B * NC, 256, 0, stream>>>(sc, out_attw);
  k_agg<<<dim3(4, 8, 8), 256, 0, stream>>>(sc, te, agg);
  k_ctx<<<dim3(8, 4, 4), 256, 0, stream>>>(agg, Wv, ctx);
  k_out<<<dim3(16, 4, 2), 256, 0, stream>>>(ctx, bv, Wo, outp);
  k_rms<<<B * NC, 256, 0, stream>>>(outp, bo, rmsw, out_comp);
}